// Round 1
// baseline (718.699 us; speedup 1.0000x reference)
//
#include <hip/hip_runtime.h>
#include <hip/hip_bf16.h>
#include <math.h>

#define N 384
#define D 256
#define R 64
#define RELH 128
#define NN (N*N)
#define ND (N*D)

// ---------------------------------------------------------------------------
// Precompute A[i,d] = h_i . ngate_w[64+t, d], B[j,d] = h_j . ngate_w[320+t, d]
// u[i] = h_i . war_w[64:320], v[j] = h_j . war_w[320:576]
// ---------------------------------------------------------------------------
__global__ void precompute_kernel(const float* __restrict__ self_h,
                                  const float* __restrict__ ngate_w,
                                  const float* __restrict__ war_w,
                                  float* __restrict__ A, float* __restrict__ B,
                                  float* __restrict__ u, float* __restrict__ v) {
    __shared__ float hrow[D];
    __shared__ float red[8];
    int i = blockIdx.x, d = threadIdx.x;
    hrow[d] = self_h[i * D + d];
    __syncthreads();
    float a = 0.f, b = 0.f;
    #pragma unroll 4
    for (int t = 0; t < D; ++t) {
        float h = hrow[t];
        a = fmaf(h, ngate_w[(R + t) * D + d], a);
        b = fmaf(h, ngate_w[(R + D + t) * D + d], b);
    }
    A[i * D + d] = a;
    B[i * D + d] = b;
    float pu = hrow[d] * war_w[R + d];
    float pv = hrow[d] * war_w[R + D + d];
    for (int off = 32; off; off >>= 1) {
        pu += __shfl_down(pu, off);
        pv += __shfl_down(pv, off);
    }
    int lane = d & 63, w = d >> 6;
    if (lane == 0) { red[w] = pu; red[4 + w] = pv; }
    __syncthreads();
    if (d == 0) {
        u[i] = red[0] + red[1] + red[2] + red[3];
        v[i] = red[4] + red[5] + red[6] + red[7];
    }
}

// ---------------------------------------------------------------------------
// tt[i,j] = r_ij . war_w[0:64] + u[i] + v[j] + war_b
// One wave (64 lanes) per pair; 4 pairs per block.
// ---------------------------------------------------------------------------
__global__ void tt_kernel(const float* __restrict__ corr,
                          const float* __restrict__ rel_w1, const float* __restrict__ rel_b1,
                          const float* __restrict__ rel_w2, const float* __restrict__ rel_b2,
                          const float* __restrict__ war_w, const float* __restrict__ war_b,
                          const float* __restrict__ u, const float* __restrict__ v,
                          float* __restrict__ tt) {
    __shared__ float h1[4][RELH];
    int tid = threadIdx.x;
    int w = tid >> 6, l = tid & 63;
    int p = blockIdx.x * 4 + w;          // pair index, grid sized exactly
    int i = p / N, j = p - i * N;
    float x0 = corr[p * 2 + 0], x1 = corr[p * 2 + 1];
    h1[w][l]      = fmaxf(0.f, fmaf(x1, rel_w1[RELH + l],      fmaf(x0, rel_w1[l],      rel_b1[l])));
    h1[w][l + 64] = fmaxf(0.f, fmaf(x1, rel_w1[RELH + l + 64], fmaf(x0, rel_w1[l + 64], rel_b1[l + 64])));
    __syncthreads();
    float acc = rel_b2[l];
    #pragma unroll 8
    for (int k = 0; k < RELH; ++k) acc = fmaf(h1[w][k], rel_w2[k * R + l], acc);
    float rm = fmaxf(0.f, acc);
    float part = rm * war_w[l];
    for (int off = 32; off; off >>= 1) part += __shfl_down(part, off);
    if (l == 0) tt[p] = part + u[i] + v[j] + war_b[0];
}

// ---------------------------------------------------------------------------
// Row softmax over valid entries (mask && tt != 0), zeros elsewhere.
// ---------------------------------------------------------------------------
__global__ void softmax_kernel(const float* __restrict__ tt,
                               const int* __restrict__ nei,
                               float* __restrict__ pos) {
    __shared__ float red[4];
    __shared__ float sM, sS;
    int i = blockIdx.x, tid = threadIdx.x;
    float tv[2]; bool valid[2];
    float m = -INFINITY;
    for (int s = 0; s < 2; ++s) {
        int j = tid + s * 256;
        valid[s] = false; tv[s] = 0.f;
        if (j < N) {
            float t = tt[i * N + j];
            bool va = (nei[i * N + j] > 0) && (t != 0.f);
            tv[s] = t; valid[s] = va;
            if (va) m = fmaxf(m, t);
        }
    }
    for (int off = 32; off; off >>= 1) m = fmaxf(m, __shfl_down(m, off));
    if ((tid & 63) == 0) red[tid >> 6] = m;
    __syncthreads();
    if (tid == 0) sM = fmaxf(fmaxf(red[0], red[1]), fmaxf(red[2], red[3]));
    __syncthreads();
    float M = sM;
    float e[2] = {0.f, 0.f};
    float sum = 0.f;
    if (M != -INFINITY) {
        for (int s = 0; s < 2; ++s)
            if (valid[s]) { e[s] = expf(tv[s] - M); sum += e[s]; }
    }
    for (int off = 32; off; off >>= 1) sum += __shfl_down(sum, off);
    if ((tid & 63) == 0) red[tid >> 6] = sum;
    __syncthreads();
    if (tid == 0) sS = red[0] + red[1] + red[2] + red[3];
    __syncthreads();
    float denom = sS;
    for (int s = 0; s < 2; ++s) {
        int j = tid + s * 256;
        if (j < N) pos[i * N + j] = (valid[s] && denom > 0.f) ? e[s] / denom : 0.f;
    }
}

// ---------------------------------------------------------------------------
// hsum[i,d] = sum_j pos[i,j] * h_j[d] * sigmoid(ngate_b[d] + A[i,d] + B[j,d]
//                                               + r_ij . ngate_w[0:64, d])
// Block per row; chunks of 4 j (one wave computes r per j), then all 256
// threads do the 64-MAC gate dot per active j.
// ---------------------------------------------------------------------------
__global__ void gate_kernel(const float* __restrict__ corr,
                            const float* __restrict__ rel_w1, const float* __restrict__ rel_b1,
                            const float* __restrict__ rel_w2, const float* __restrict__ rel_b2,
                            const float* __restrict__ ngate_w, const float* __restrict__ ngate_b,
                            const float* __restrict__ A, const float* __restrict__ Bm,
                            const float* __restrict__ pos, const float* __restrict__ self_h,
                            float* __restrict__ hsum) {
    __shared__ float h1[4][RELH];
    __shared__ float rs[4][R];
    __shared__ float wsh[4];
    int i = blockIdx.x, tid = threadIdx.x;
    int w = tid >> 6, l = tid & 63;
    float base = ngate_b[tid] + A[i * D + tid];
    float acc = 0.f;
    for (int j0 = 0; j0 < N; j0 += 4) {
        int j = j0 + w;
        float wt = pos[i * N + j];
        if (l == 0) wsh[w] = wt;
        if (wt != 0.f) {
            int p = i * N + j;
            float x0 = corr[p * 2], x1 = corr[p * 2 + 1];
            h1[w][l]      = fmaxf(0.f, fmaf(x1, rel_w1[RELH + l],      fmaf(x0, rel_w1[l],      rel_b1[l])));
            h1[w][l + 64] = fmaxf(0.f, fmaf(x1, rel_w1[RELH + l + 64], fmaf(x0, rel_w1[l + 64], rel_b1[l + 64])));
        }
        __syncthreads();
        if (wsh[w] != 0.f) {
            float a2 = rel_b2[l];
            #pragma unroll 8
            for (int k = 0; k < RELH; ++k) a2 = fmaf(h1[w][k], rel_w2[k * R + l], a2);
            rs[w][l] = fmaxf(0.f, a2);
        }
        __syncthreads();
        #pragma unroll
        for (int ww = 0; ww < 4; ++ww) {
            float wtj = wsh[ww];
            if (wtj != 0.f) {
                int jj = j0 + ww;
                float logit = base + Bm[jj * D + tid];
                #pragma unroll 8
                for (int m = 0; m < R; ++m) logit = fmaf(rs[ww][m], ngate_w[m * D + tid], logit);
                float g = 1.f / (1.f + expf(-logit));
                acc = fmaf(wtj * self_h[jj * D + tid], g, acc);
            }
        }
        __syncthreads();
    }
    hsum[i * D + tid] = acc;
}

// ---------------------------------------------------------------------------
// hidden = relu(hsum @ W1 + b1); out2 = hidden @ W2 + b2;
// C = out2 + self_c; H_out = outgate * tanh(C); outputs = (outgate, H_out, C)
// ---------------------------------------------------------------------------
__global__ void final_kernel(const float* __restrict__ hsum,
                             const float* __restrict__ wnei_w1, const float* __restrict__ wnei_b1,
                             const float* __restrict__ wnei_w2, const float* __restrict__ wnei_b2,
                             const float* __restrict__ self_c, const float* __restrict__ outgate,
                             float* __restrict__ out) {
    __shared__ float hs[D];
    __shared__ float hid[D];
    int i = blockIdx.x, d = threadIdx.x;
    hs[d] = hsum[i * D + d];
    __syncthreads();
    float a = wnei_b1[d];
    #pragma unroll 4
    for (int t = 0; t < D; ++t) a = fmaf(hs[t], wnei_w1[t * D + d], a);
    hid[d] = fmaxf(0.f, a);
    __syncthreads();
    float b = wnei_b2[d];
    #pragma unroll 4
    for (int t = 0; t < D; ++t) b = fmaf(hid[t], wnei_w2[t * D + d], b);
    int idx = i * D + d;
    float C = b + self_c[idx];
    float og = outgate[idx];
    out[idx] = og;
    out[ND + idx] = og * tanhf(C);
    out[2 * ND + idx] = C;
}

extern "C" void kernel_launch(void* const* d_in, const int* in_sizes, int n_in,
                              void* d_out, int out_size, void* d_ws, size_t ws_size,
                              hipStream_t stream) {
    const float* corr    = (const float*)d_in[0];
    const int*   nei     = (const int*)d_in[1];
    // d_in[2] = nei_num (unused by reference)
    const float* outg    = (const float*)d_in[3];
    const float* self_h  = (const float*)d_in[4];
    const float* self_c  = (const float*)d_in[5];
    const float* rel_w1  = (const float*)d_in[6];
    const float* rel_b1  = (const float*)d_in[7];
    const float* rel_w2  = (const float*)d_in[8];
    const float* rel_b2  = (const float*)d_in[9];
    const float* ngate_w = (const float*)d_in[10];
    const float* ngate_b = (const float*)d_in[11];
    const float* war_w   = (const float*)d_in[12];
    const float* war_b   = (const float*)d_in[13];
    const float* wnei_w1 = (const float*)d_in[14];
    const float* wnei_b1 = (const float*)d_in[15];
    const float* wnei_w2 = (const float*)d_in[16];
    const float* wnei_b2 = (const float*)d_in[17];

    float* ws   = (float*)d_ws;
    float* tt   = ws;                  // N*N
    float* pos  = ws + NN;             // N*N
    float* A    = ws + 2 * NN;         // N*D
    float* Bm   = ws + 2 * NN + ND;    // N*D
    float* u    = ws + 2 * NN + 2 * ND;        // N
    float* v    = ws + 2 * NN + 2 * ND + N;    // N
    float* hsum = ws + 2 * NN + 2 * ND + 2 * N; // N*D
    float* out  = (float*)d_out;

    precompute_kernel<<<N, 256, 0, stream>>>(self_h, ngate_w, war_w, A, Bm, u, v);
    tt_kernel<<<NN / 4, 256, 0, stream>>>(corr, rel_w1, rel_b1, rel_w2, rel_b2,
                                          war_w, war_b, u, v, tt);
    softmax_kernel<<<N, 256, 0, stream>>>(tt, nei, pos);
    gate_kernel<<<N, 256, 0, stream>>>(corr, rel_w1, rel_b1, rel_w2, rel_b2,
                                       ngate_w, ngate_b, A, Bm, pos, self_h, hsum);
    final_kernel<<<N, 256, 0, stream>>>(hsum, wnei_w1, wnei_b1, wnei_w2, wnei_b2,
                                        self_c, outg, out);
}

// Round 2
// 368.781 us; speedup vs baseline: 1.9489x; 1.9489x over previous
//
#include <hip/hip_runtime.h>
#include <hip/hip_bf16.h>
#include <math.h>

#define N 384
#define D 256
#define R 64
#define RELH 128
#define NN (N*N)
#define ND (N*D)
#define JCHUNK 64
#define NCHUNK (N / JCHUNK)   // 6

// ---------------------------------------------------------------------------
// Precompute A[i,d] = h_i . ngate_w[64+t, d], B[j,d] = h_j . ngate_w[320+t, d]
// u[i] = h_i . war_w[64:320], v[j] = h_j . war_w[320:576]
// ---------------------------------------------------------------------------
__global__ void precompute_kernel(const float* __restrict__ self_h,
                                  const float* __restrict__ ngate_w,
                                  const float* __restrict__ war_w,
                                  float* __restrict__ A, float* __restrict__ B,
                                  float* __restrict__ u, float* __restrict__ v) {
    __shared__ float hrow[D];
    __shared__ float red[8];
    int i = blockIdx.x, d = threadIdx.x;
    hrow[d] = self_h[i * D + d];
    __syncthreads();
    float a0 = 0.f, a1 = 0.f, b0 = 0.f, b1 = 0.f;
    const float4* hv = (const float4*)hrow;
    #pragma unroll 4
    for (int t4 = 0; t4 < D / 4; ++t4) {
        float4 h = hv[t4];
        int t = t4 * 4;
        a0 = fmaf(h.x, ngate_w[(R + t) * D + d], a0);
        a1 = fmaf(h.y, ngate_w[(R + t + 1) * D + d], a1);
        a0 = fmaf(h.z, ngate_w[(R + t + 2) * D + d], a0);
        a1 = fmaf(h.w, ngate_w[(R + t + 3) * D + d], a1);
        b0 = fmaf(h.x, ngate_w[(R + D + t) * D + d], b0);
        b1 = fmaf(h.y, ngate_w[(R + D + t + 1) * D + d], b1);
        b0 = fmaf(h.z, ngate_w[(R + D + t + 2) * D + d], b0);
        b1 = fmaf(h.w, ngate_w[(R + D + t + 3) * D + d], b1);
    }
    A[i * D + d] = a0 + a1;
    B[i * D + d] = b0 + b1;
    float pu = hrow[d] * war_w[R + d];
    float pv = hrow[d] * war_w[R + D + d];
    for (int off = 32; off; off >>= 1) {
        pu += __shfl_down(pu, off);
        pv += __shfl_down(pv, off);
    }
    int lane = d & 63, w = d >> 6;
    if (lane == 0) { red[w] = pu; red[4 + w] = pv; }
    __syncthreads();
    if (d == 0) {
        u[i] = red[0] + red[1] + red[2] + red[3];
        v[i] = red[4] + red[5] + red[6] + red[7];
    }
}

// ---------------------------------------------------------------------------
// tt[i,j] = r_ij . war_w[0:64] + u[i] + v[j] + war_b ; optionally store r.
// One wave per pair; 4 pairs per block.
// ---------------------------------------------------------------------------
__global__ void tt_kernel(const float* __restrict__ corr,
                          const float* __restrict__ rel_w1, const float* __restrict__ rel_b1,
                          const float* __restrict__ rel_w2, const float* __restrict__ rel_b2,
                          const float* __restrict__ war_w, const float* __restrict__ war_b,
                          const float* __restrict__ u, const float* __restrict__ v,
                          float* __restrict__ tt, float* __restrict__ rc) {
    __shared__ __align__(16) float h1[4][RELH];
    int tid = threadIdx.x;
    int w = tid >> 6, l = tid & 63;
    int p = blockIdx.x * 4 + w;          // pair index, grid sized exactly
    int i = p / N, j = p - i * N;
    float x0 = corr[p * 2 + 0], x1 = corr[p * 2 + 1];
    h1[w][l]      = fmaxf(0.f, fmaf(x1, rel_w1[RELH + l],      fmaf(x0, rel_w1[l],      rel_b1[l])));
    h1[w][l + 64] = fmaxf(0.f, fmaf(x1, rel_w1[RELH + l + 64], fmaf(x0, rel_w1[l + 64], rel_b1[l + 64])));
    __syncthreads();
    float c0 = rel_b2[l], c1 = 0.f, c2 = 0.f, c3 = 0.f;
    const float4* hv = (const float4*)h1[w];
    #pragma unroll 8
    for (int k4 = 0; k4 < RELH / 4; ++k4) {
        float4 h = hv[k4];
        int k = k4 * 4;
        c0 = fmaf(h.x, rel_w2[k * R + l], c0);
        c1 = fmaf(h.y, rel_w2[(k + 1) * R + l], c1);
        c2 = fmaf(h.z, rel_w2[(k + 2) * R + l], c2);
        c3 = fmaf(h.w, rel_w2[(k + 3) * R + l], c3);
    }
    float rm = fmaxf(0.f, (c0 + c1) + (c2 + c3));
    if (rc) rc[p * R + l] = rm;
    float part = rm * war_w[l];
    for (int off = 32; off; off >>= 1) part += __shfl_down(part, off);
    if (l == 0) tt[p] = part + u[i] + v[j] + war_b[0];
}

// ---------------------------------------------------------------------------
// Row softmax over valid entries (mask && tt != 0), zeros elsewhere.
// ---------------------------------------------------------------------------
__global__ void softmax_kernel(const float* __restrict__ tt,
                               const int* __restrict__ nei,
                               float* __restrict__ pos) {
    __shared__ float red[4];
    __shared__ float sM, sS;
    int i = blockIdx.x, tid = threadIdx.x;
    float tv[2]; bool valid[2];
    float m = -INFINITY;
    for (int s = 0; s < 2; ++s) {
        int j = tid + s * 256;
        valid[s] = false; tv[s] = 0.f;
        if (j < N) {
            float t = tt[i * N + j];
            bool va = (nei[i * N + j] > 0) && (t != 0.f);
            tv[s] = t; valid[s] = va;
            if (va) m = fmaxf(m, t);
        }
    }
    for (int off = 32; off; off >>= 1) m = fmaxf(m, __shfl_down(m, off));
    if ((tid & 63) == 0) red[tid >> 6] = m;
    __syncthreads();
    if (tid == 0) sM = fmaxf(fmaxf(red[0], red[1]), fmaxf(red[2], red[3]));
    __syncthreads();
    float M = sM;
    float e[2] = {0.f, 0.f};
    float sum = 0.f;
    if (M != -INFINITY) {
        for (int s = 0; s < 2; ++s)
            if (valid[s]) { e[s] = expf(tv[s] - M); sum += e[s]; }
    }
    for (int off = 32; off; off >>= 1) sum += __shfl_down(sum, off);
    if ((tid & 63) == 0) red[tid >> 6] = sum;
    __syncthreads();
    if (tid == 0) sS = red[0] + red[1] + red[2] + red[3];
    __syncthreads();
    float denom = sS;
    for (int s = 0; s < 2; ++s) {
        int j = tid + s * 256;
        if (j < N) pos[i * N + j] = (valid[s] && denom > 0.f) ? e[s] / denom : 0.f;
    }
}

// ---------------------------------------------------------------------------
// partial[(c*N+i)*D+d] = sum_{j in chunk c} pos[i,j]*h_j[d]*sigmoid(
//     ngate_b[d] + A[i,d] + B[j,d] + r_ij . ngate_w[0:64, d])
// Grid (N, NCHUNK); block 256. RC: load cached r; else recompute rel MLP.
// ---------------------------------------------------------------------------
template<bool RC>
__global__ void gate_kernel(const float* __restrict__ corr,
                            const float* __restrict__ rel_w1, const float* __restrict__ rel_b1,
                            const float* __restrict__ rel_w2, const float* __restrict__ rel_b2,
                            const float* __restrict__ ngate_w, const float* __restrict__ ngate_b,
                            const float* __restrict__ A, const float* __restrict__ Bm,
                            const float* __restrict__ pos, const float* __restrict__ self_h,
                            const float* __restrict__ rcache,
                            float* __restrict__ partial) {
    __shared__ __align__(16) float h1[4][RELH];
    __shared__ __align__(16) float rs[4][R];
    __shared__ float wsh[4];
    int i = blockIdx.x, tid = threadIdx.x;
    int jbase = blockIdx.y * JCHUNK;
    int w = tid >> 6, l = tid & 63;
    // zero rs so inactive slots never feed NaN garbage into the (guarded) dot
    ((float*)rs)[tid] = 0.f;
    float base = ngate_b[tid] + A[i * D + tid];
    float acc = 0.f;
    for (int j0 = jbase; j0 < jbase + JCHUNK; j0 += 4) {
        int j = j0 + w;
        int p = i * N + j;
        float wt = pos[p];
        if (l == 0) wsh[w] = wt;
        if (wt != 0.f) {
            if (RC) {
                rs[w][l] = rcache[p * R + l];
            } else {
                float x0 = corr[p * 2], x1 = corr[p * 2 + 1];
                h1[w][l]      = fmaxf(0.f, fmaf(x1, rel_w1[RELH + l],      fmaf(x0, rel_w1[l],      rel_b1[l])));
                h1[w][l + 64] = fmaxf(0.f, fmaf(x1, rel_w1[RELH + l + 64], fmaf(x0, rel_w1[l + 64], rel_b1[l + 64])));
            }
        }
        __syncthreads();
        if (!RC) {
            if (wsh[w] != 0.f) {
                float c0 = rel_b2[l], c1 = 0.f, c2 = 0.f, c3 = 0.f;
                const float4* hv = (const float4*)h1[w];
                #pragma unroll 8
                for (int k4 = 0; k4 < RELH / 4; ++k4) {
                    float4 h = hv[k4];
                    int k = k4 * 4;
                    c0 = fmaf(h.x, rel_w2[k * R + l], c0);
                    c1 = fmaf(h.y, rel_w2[(k + 1) * R + l], c1);
                    c2 = fmaf(h.z, rel_w2[(k + 2) * R + l], c2);
                    c3 = fmaf(h.w, rel_w2[(k + 3) * R + l], c3);
                }
                rs[w][l] = fmaxf(0.f, (c0 + c1) + (c2 + c3));
            }
            __syncthreads();
        }
        #pragma unroll
        for (int ww = 0; ww < 4; ++ww) {
            float wtj = wsh[ww];          // block-uniform -> no divergence
            if (wtj != 0.f) {
                int jj = j0 + ww;
                const float4* rv = (const float4*)rs[ww];
                float l0 = 0.f, l1 = 0.f, l2 = 0.f, l3 = 0.f;
                #pragma unroll 4
                for (int m4 = 0; m4 < R / 4; ++m4) {
                    float4 r4 = rv[m4];
                    int m = m4 * 4;
                    l0 = fmaf(r4.x, ngate_w[m * D + tid], l0);
                    l1 = fmaf(r4.y, ngate_w[(m + 1) * D + tid], l1);
                    l2 = fmaf(r4.z, ngate_w[(m + 2) * D + tid], l2);
                    l3 = fmaf(r4.w, ngate_w[(m + 3) * D + tid], l3);
                }
                float logit = base + Bm[jj * D + tid] + ((l0 + l1) + (l2 + l3));
                float g = 1.f / (1.f + expf(-logit));
                acc = fmaf(wtj * self_h[jj * D + tid], g, acc);
            }
        }
        __syncthreads();
    }
    partial[(blockIdx.y * N + i) * D + tid] = acc;
}

// ---------------------------------------------------------------------------
// hsum = sum of partials; hidden = relu(hsum@W1+b1); out2 = hidden@W2+b2;
// C = out2 + self_c; H_out = outgate * tanh(C); outputs = (outgate, H_out, C)
// ---------------------------------------------------------------------------
__global__ void final_kernel(const float* __restrict__ partial,
                             const float* __restrict__ wnei_w1, const float* __restrict__ wnei_b1,
                             const float* __restrict__ wnei_w2, const float* __restrict__ wnei_b2,
                             const float* __restrict__ self_c, const float* __restrict__ outgate,
                             float* __restrict__ out) {
    __shared__ __align__(16) float hs[D];
    __shared__ __align__(16) float hid[D];
    int i = blockIdx.x, d = threadIdx.x;
    float s = 0.f;
    #pragma unroll
    for (int c = 0; c < NCHUNK; ++c) s += partial[(c * N + i) * D + d];
    hs[d] = s;
    __syncthreads();
    float a0 = wnei_b1[d], a1 = 0.f, a2 = 0.f, a3 = 0.f;
    const float4* hv = (const float4*)hs;
    #pragma unroll 4
    for (int t4 = 0; t4 < D / 4; ++t4) {
        float4 h = hv[t4];
        int t = t4 * 4;
        a0 = fmaf(h.x, wnei_w1[t * D + d], a0);
        a1 = fmaf(h.y, wnei_w1[(t + 1) * D + d], a1);
        a2 = fmaf(h.z, wnei_w1[(t + 2) * D + d], a2);
        a3 = fmaf(h.w, wnei_w1[(t + 3) * D + d], a3);
    }
    hid[d] = fmaxf(0.f, (a0 + a1) + (a2 + a3));
    __syncthreads();
    float b0 = wnei_b2[d], b1 = 0.f, b2 = 0.f, b3 = 0.f;
    const float4* gv = (const float4*)hid;
    #pragma unroll 4
    for (int t4 = 0; t4 < D / 4; ++t4) {
        float4 h = gv[t4];
        int t = t4 * 4;
        b0 = fmaf(h.x, wnei_w2[t * D + d], b0);
        b1 = fmaf(h.y, wnei_w2[(t + 1) * D + d], b1);
        b2 = fmaf(h.z, wnei_w2[(t + 2) * D + d], b2);
        b3 = fmaf(h.w, wnei_w2[(t + 3) * D + d], b3);
    }
    int idx = i * D + d;
    float C = (b0 + b1) + (b2 + b3) + self_c[idx];
    float og = outgate[idx];
    out[idx] = og;
    out[ND + idx] = og * tanhf(C);
    out[2 * ND + idx] = C;
}

extern "C" void kernel_launch(void* const* d_in, const int* in_sizes, int n_in,
                              void* d_out, int out_size, void* d_ws, size_t ws_size,
                              hipStream_t stream) {
    const float* corr    = (const float*)d_in[0];
    const int*   nei     = (const int*)d_in[1];
    const float* outg    = (const float*)d_in[3];
    const float* self_h  = (const float*)d_in[4];
    const float* self_c  = (const float*)d_in[5];
    const float* rel_w1  = (const float*)d_in[6];
    const float* rel_b1  = (const float*)d_in[7];
    const float* rel_w2  = (const float*)d_in[8];
    const float* rel_b2  = (const float*)d_in[9];
    const float* ngate_w = (const float*)d_in[10];
    const float* ngate_b = (const float*)d_in[11];
    const float* war_w   = (const float*)d_in[12];
    const float* war_b   = (const float*)d_in[13];
    const float* wnei_w1 = (const float*)d_in[14];
    const float* wnei_b1 = (const float*)d_in[15];
    const float* wnei_w2 = (const float*)d_in[16];
    const float* wnei_b2 = (const float*)d_in[17];

    float* ws      = (float*)d_ws;
    float* tt      = ws;                       // NN
    float* pos     = ws + NN;                  // NN
    float* A       = ws + 2 * NN;              // ND
    float* Bm      = ws + 2 * NN + ND;         // ND
    float* u       = ws + 2 * NN + 2 * ND;     // N
    float* v       = u + N;                    // N
    float* partial = v + N;                    // NCHUNK*ND
    float* rcache  = partial + NCHUNK * ND;    // NN*R (optional)
    size_t base_floats = (size_t)(2 * NN + 2 * ND + 2 * N + NCHUNK * ND);
    bool use_rc = ws_size >= (base_floats + (size_t)NN * R) * sizeof(float);
    float* out = (float*)d_out;

    precompute_kernel<<<N, 256, 0, stream>>>(self_h, ngate_w, war_w, A, Bm, u, v);
    tt_kernel<<<NN / 4, 256, 0, stream>>>(corr, rel_w1, rel_b1, rel_w2, rel_b2,
                                          war_w, war_b, u, v, tt,
                                          use_rc ? rcache : nullptr);
    softmax_kernel<<<N, 256, 0, stream>>>(tt, nei, pos);
    dim3 ggrid(N, NCHUNK);
    if (use_rc) {
        gate_kernel<true><<<ggrid, 256, 0, stream>>>(corr, rel_w1, rel_b1, rel_w2, rel_b2,
                                                     ngate_w, ngate_b, A, Bm, pos, self_h,
                                                     rcache, partial);
    } else {
        gate_kernel<false><<<ggrid, 256, 0, stream>>>(corr, rel_w1, rel_b1, rel_w2, rel_b2,
                                                      ngate_w, ngate_b, A, Bm, pos, self_h,
                                                      nullptr, partial);
    }
    final_kernel<<<N, 256, 0, stream>>>(partial, wnei_w1, wnei_b1, wnei_w2, wnei_b2,
                                        self_c, outg, out);
}

// Round 3
// 189.375 us; speedup vs baseline: 3.7951x; 1.9474x over previous
//
#include <hip/hip_runtime.h>
#include <hip/hip_bf16.h>
#include <math.h>

#define N 384
#define D 256
#define R 64
#define RELH 128
#define NN (N*N)
#define ND (N*D)
#define JCHUNK 64
#define NCHUNK (N / JCHUNK)   // 6
#define TPB 16                // tt pairs per block

// ---------------------------------------------------------------------------
// Precompute A[i,d] = h_i . ngate_w[64+t, d], B[j,d] = h_j . ngate_w[320+t, d]
// u[i] = h_i . war_w[64:320], v[j] = h_j . war_w[320:576]
// ---------------------------------------------------------------------------
__global__ void precompute_kernel(const float* __restrict__ self_h,
                                  const float* __restrict__ ngate_w,
                                  const float* __restrict__ war_w,
                                  float* __restrict__ A, float* __restrict__ B,
                                  float* __restrict__ u, float* __restrict__ v) {
    __shared__ float hrow[D];
    __shared__ float red[8];
    int i = blockIdx.x, d = threadIdx.x;
    hrow[d] = self_h[i * D + d];
    __syncthreads();
    float a0 = 0.f, a1 = 0.f, b0 = 0.f, b1 = 0.f;
    const float4* hv = (const float4*)hrow;
    #pragma unroll 4
    for (int t4 = 0; t4 < D / 4; ++t4) {
        float4 h = hv[t4];
        int t = t4 * 4;
        a0 = fmaf(h.x, ngate_w[(R + t) * D + d], a0);
        a1 = fmaf(h.y, ngate_w[(R + t + 1) * D + d], a1);
        a0 = fmaf(h.z, ngate_w[(R + t + 2) * D + d], a0);
        a1 = fmaf(h.w, ngate_w[(R + t + 3) * D + d], a1);
        b0 = fmaf(h.x, ngate_w[(R + D + t) * D + d], b0);
        b1 = fmaf(h.y, ngate_w[(R + D + t + 1) * D + d], b1);
        b0 = fmaf(h.z, ngate_w[(R + D + t + 2) * D + d], b0);
        b1 = fmaf(h.w, ngate_w[(R + D + t + 3) * D + d], b1);
    }
    A[i * D + d] = a0 + a1;
    B[i * D + d] = b0 + b1;
    float pu = hrow[d] * war_w[R + d];
    float pv = hrow[d] * war_w[R + D + d];
    for (int off = 32; off; off >>= 1) {
        pu += __shfl_down(pu, off);
        pv += __shfl_down(pv, off);
    }
    int lane = d & 63, w = d >> 6;
    if (lane == 0) { red[w] = pu; red[4 + w] = pv; }
    __syncthreads();
    if (d == 0) {
        u[i] = red[0] + red[1] + red[2] + red[3];
        v[i] = red[4] + red[5] + red[6] + red[7];
    }
}

// ---------------------------------------------------------------------------
// tt[i,j] = r_ij . war_w[0:64] + u[i] + v[j] + war_b ; store r to rcache.
// rel_w2 column hoisted into 128 VGPRs (amortized over TPB pairs per block).
// One wave per pair; no barriers (h1 round-trip is same-wave).
// ---------------------------------------------------------------------------
__global__ __launch_bounds__(256) void tt_kernel(
        const float* __restrict__ corr,
        const float* __restrict__ rel_w1, const float* __restrict__ rel_b1,
        const float* __restrict__ rel_w2, const float* __restrict__ rel_b2,
        const float* __restrict__ war_w, const float* __restrict__ war_b,
        const float* __restrict__ u, const float* __restrict__ v,
        float* __restrict__ tt, float* __restrict__ rc) {
    __shared__ __align__(16) float h1s[4][RELH];
    int tid = threadIdx.x, w = tid >> 6, l = tid & 63;
    float w2col[RELH];
    #pragma unroll
    for (int k = 0; k < RELH; ++k) w2col[k] = rel_w2[k * R + l];
    float w1a0 = rel_w1[l],      w1a1 = rel_w1[RELH + l];
    float w1b0 = rel_w1[64 + l], w1b1 = rel_w1[RELH + 64 + l];
    float b1a = rel_b1[l], b1b = rel_b1[64 + l];
    float b2v = rel_b2[l], warw = war_w[l], wb = war_b[0];
    int pbase = blockIdx.x * TPB;
    #pragma unroll
    for (int it = 0; it < TPB / 4; ++it) {
        int p = pbase + it * 4 + w;
        int i = p / N, j = p - i * N;
        float2 x = *(const float2*)(corr + p * 2);
        h1s[w][l]      = fmaxf(0.f, fmaf(x.y, w1a1, fmaf(x.x, w1a0, b1a)));
        h1s[w][l + 64] = fmaxf(0.f, fmaf(x.y, w1b1, fmaf(x.x, w1b0, b1b)));
        float c0 = b2v, c1 = 0.f, c2 = 0.f, c3 = 0.f;
        const float4* hv = (const float4*)h1s[w];
        #pragma unroll
        for (int k4 = 0; k4 < RELH / 4; ++k4) {
            float4 h = hv[k4];
            c0 = fmaf(h.x, w2col[k4 * 4 + 0], c0);
            c1 = fmaf(h.y, w2col[k4 * 4 + 1], c1);
            c2 = fmaf(h.z, w2col[k4 * 4 + 2], c2);
            c3 = fmaf(h.w, w2col[k4 * 4 + 3], c3);
        }
        float rm = fmaxf(0.f, (c0 + c1) + (c2 + c3));
        if (rc) rc[(size_t)p * R + l] = rm;
        float part = rm * warw;
        for (int off = 32; off; off >>= 1) part += __shfl_down(part, off);
        if (l == 0) tt[p] = part + u[i] + v[j] + wb;
    }
}

// ---------------------------------------------------------------------------
// Row softmax over valid entries (mask && tt != 0), zeros elsewhere.
// ---------------------------------------------------------------------------
__global__ void softmax_kernel(const float* __restrict__ tt,
                               const int* __restrict__ nei,
                               float* __restrict__ pos) {
    __shared__ float red[4];
    __shared__ float sM, sS;
    int i = blockIdx.x, tid = threadIdx.x;
    float tv[2]; bool valid[2];
    float m = -INFINITY;
    for (int s = 0; s < 2; ++s) {
        int j = tid + s * 256;
        valid[s] = false; tv[s] = 0.f;
        if (j < N) {
            float t = tt[i * N + j];
            bool va = (nei[i * N + j] > 0) && (t != 0.f);
            tv[s] = t; valid[s] = va;
            if (va) m = fmaxf(m, t);
        }
    }
    for (int off = 32; off; off >>= 1) m = fmaxf(m, __shfl_down(m, off));
    if ((tid & 63) == 0) red[tid >> 6] = m;
    __syncthreads();
    if (tid == 0) sM = fmaxf(fmaxf(red[0], red[1]), fmaxf(red[2], red[3]));
    __syncthreads();
    float M = sM;
    float e[2] = {0.f, 0.f};
    float sum = 0.f;
    if (M != -INFINITY) {
        for (int s = 0; s < 2; ++s)
            if (valid[s]) { e[s] = expf(tv[s] - M); sum += e[s]; }
    }
    for (int off = 32; off; off >>= 1) sum += __shfl_down(sum, off);
    if ((tid & 63) == 0) red[tid >> 6] = sum;
    __syncthreads();
    if (tid == 0) sS = red[0] + red[1] + red[2] + red[3];
    __syncthreads();
    float denom = sS;
    for (int s = 0; s < 2; ++s) {
        int j = tid + s * 256;
        if (j < N) pos[i * N + j] = (valid[s] && denom > 0.f) ? e[s] / denom : 0.f;
    }
}

// ---------------------------------------------------------------------------
// gate v3 (rcache path): ngate_w[0:64, tid] hoisted into 64 VGPRs; whole
// 64-j chunk of r staged into LDS with one bulk copy + one barrier;
// compacted active-j list via ballot; unconditional inner loop.
// partial[(c*N+i)*D+d] = sum_{j in chunk} pos*h_j*sigmoid(...)
// ---------------------------------------------------------------------------
__global__ __launch_bounds__(256) void gate_rc_kernel(
        const float* __restrict__ ngate_w, const float* __restrict__ ngate_b,
        const float* __restrict__ A, const float* __restrict__ Bm,
        const float* __restrict__ pos, const float* __restrict__ self_h,
        const float* __restrict__ rcache, float* __restrict__ partial) {
    __shared__ __align__(16) float rsall[JCHUNK][R];   // 16 KB
    __shared__ float posv[JCHUNK];
    __shared__ int jlist[JCHUNK];
    __shared__ int scnt;
    int i = blockIdx.x, tid = threadIdx.x;
    int jbase = blockIdx.y * JCHUNK;
    float wreg[R];
    #pragma unroll
    for (int m = 0; m < R; ++m) wreg[m] = ngate_w[m * D + tid];
    float base = ngate_b[tid] + A[i * D + tid];
    // bulk-stage rcache chunk: 64*64 floats = 1024 float4, contiguous
    const float4* src = (const float4*)(rcache + (size_t)(i * N + jbase) * R);
    float4* dst = (float4*)rsall;
    #pragma unroll
    for (int s = 0; s < 4; ++s) dst[tid + s * 256] = src[tid + s * 256];
    if (tid < JCHUNK) {
        float pv = pos[i * N + jbase + tid];
        posv[tid] = pv;
        bool act = pv != 0.f;
        unsigned long long mask = __ballot(act);
        int pre = __popcll(mask & ((1ull << tid) - 1));
        if (act) jlist[pre] = tid;
        if (tid == 0) scnt = (int)__popcll(mask);
    }
    __syncthreads();
    int cnt = scnt;
    float acc = 0.f;
    for (int c = 0; c < cnt; ++c) {
        int j = jlist[c];
        int jj = jbase + j;
        float wt = posv[j];
        float bmv = Bm[jj * D + tid];
        float hv  = self_h[jj * D + tid];
        const float4* rv = (const float4*)rsall[j];
        float l0 = 0.f, l1 = 0.f, l2 = 0.f, l3 = 0.f;
        #pragma unroll
        for (int m4 = 0; m4 < R / 4; ++m4) {
            float4 r4 = rv[m4];
            l0 = fmaf(r4.x, wreg[m4 * 4 + 0], l0);
            l1 = fmaf(r4.y, wreg[m4 * 4 + 1], l1);
            l2 = fmaf(r4.z, wreg[m4 * 4 + 2], l2);
            l3 = fmaf(r4.w, wreg[m4 * 4 + 3], l3);
        }
        float logit = base + bmv + ((l0 + l1) + (l2 + l3));
        float g = 1.f / (1.f + expf(-logit));
        acc = fmaf(wt * hv, g, acc);
    }
    partial[(blockIdx.y * N + i) * D + tid] = acc;
}

// ---------------------------------------------------------------------------
// Fallback gate (no rcache): recompute rel MLP per active pair (old version).
// ---------------------------------------------------------------------------
__global__ void gate_norc_kernel(const float* __restrict__ corr,
                            const float* __restrict__ rel_w1, const float* __restrict__ rel_b1,
                            const float* __restrict__ rel_w2, const float* __restrict__ rel_b2,
                            const float* __restrict__ ngate_w, const float* __restrict__ ngate_b,
                            const float* __restrict__ A, const float* __restrict__ Bm,
                            const float* __restrict__ pos, const float* __restrict__ self_h,
                            float* __restrict__ partial) {
    __shared__ __align__(16) float h1[4][RELH];
    __shared__ __align__(16) float rs[4][R];
    __shared__ float wsh[4];
    int i = blockIdx.x, tid = threadIdx.x;
    int jbase = blockIdx.y * JCHUNK;
    int w = tid >> 6, l = tid & 63;
    ((float*)rs)[tid] = 0.f;
    float base = ngate_b[tid] + A[i * D + tid];
    float acc = 0.f;
    for (int j0 = jbase; j0 < jbase + JCHUNK; j0 += 4) {
        int j = j0 + w;
        int p = i * N + j;
        float wt = pos[p];
        if (l == 0) wsh[w] = wt;
        if (wt != 0.f) {
            float x0 = corr[p * 2], x1 = corr[p * 2 + 1];
            h1[w][l]      = fmaxf(0.f, fmaf(x1, rel_w1[RELH + l],      fmaf(x0, rel_w1[l],      rel_b1[l])));
            h1[w][l + 64] = fmaxf(0.f, fmaf(x1, rel_w1[RELH + l + 64], fmaf(x0, rel_w1[l + 64], rel_b1[l + 64])));
        }
        __syncthreads();
        if (wsh[w] != 0.f) {
            float c0 = rel_b2[l], c1 = 0.f, c2 = 0.f, c3 = 0.f;
            const float4* hv = (const float4*)h1[w];
            #pragma unroll 8
            for (int k4 = 0; k4 < RELH / 4; ++k4) {
                float4 h = hv[k4];
                int k = k4 * 4;
                c0 = fmaf(h.x, rel_w2[k * R + l], c0);
                c1 = fmaf(h.y, rel_w2[(k + 1) * R + l], c1);
                c2 = fmaf(h.z, rel_w2[(k + 2) * R + l], c2);
                c3 = fmaf(h.w, rel_w2[(k + 3) * R + l], c3);
            }
            rs[w][l] = fmaxf(0.f, (c0 + c1) + (c2 + c3));
        }
        __syncthreads();
        #pragma unroll
        for (int ww = 0; ww < 4; ++ww) {
            float wtj = wsh[ww];
            if (wtj != 0.f) {
                int jj = j0 + ww;
                const float4* rv = (const float4*)rs[ww];
                float l0 = 0.f, l1 = 0.f, l2 = 0.f, l3 = 0.f;
                #pragma unroll 4
                for (int m4 = 0; m4 < R / 4; ++m4) {
                    float4 r4 = rv[m4];
                    int m = m4 * 4;
                    l0 = fmaf(r4.x, ngate_w[m * D + tid], l0);
                    l1 = fmaf(r4.y, ngate_w[(m + 1) * D + tid], l1);
                    l2 = fmaf(r4.z, ngate_w[(m + 2) * D + tid], l2);
                    l3 = fmaf(r4.w, ngate_w[(m + 3) * D + tid], l3);
                }
                float logit = base + Bm[jj * D + tid] + ((l0 + l1) + (l2 + l3));
                float g = 1.f / (1.f + expf(-logit));
                acc = fmaf(wtj * self_h[jj * D + tid], g, acc);
            }
        }
        __syncthreads();
    }
    partial[(blockIdx.y * N + i) * D + tid] = acc;
}

// ---------------------------------------------------------------------------
// hsum = sum of partials; hidden = relu(hsum@W1+b1); out2 = hidden@W2+b2;
// C = out2 + self_c; H_out = outgate * tanh(C); outputs = (outgate, H_out, C)
// ---------------------------------------------------------------------------
__global__ void final_kernel(const float* __restrict__ partial,
                             const float* __restrict__ wnei_w1, const float* __restrict__ wnei_b1,
                             const float* __restrict__ wnei_w2, const float* __restrict__ wnei_b2,
                             const float* __restrict__ self_c, const float* __restrict__ outgate,
                             float* __restrict__ out) {
    __shared__ __align__(16) float hs[D];
    __shared__ __align__(16) float hid[D];
    int i = blockIdx.x, d = threadIdx.x;
    float s = 0.f;
    #pragma unroll
    for (int c = 0; c < NCHUNK; ++c) s += partial[(c * N + i) * D + d];
    hs[d] = s;
    __syncthreads();
    float a0 = wnei_b1[d], a1 = 0.f, a2 = 0.f, a3 = 0.f;
    const float4* hv = (const float4*)hs;
    #pragma unroll 4
    for (int t4 = 0; t4 < D / 4; ++t4) {
        float4 h = hv[t4];
        int t = t4 * 4;
        a0 = fmaf(h.x, wnei_w1[t * D + d], a0);
        a1 = fmaf(h.y, wnei_w1[(t + 1) * D + d], a1);
        a2 = fmaf(h.z, wnei_w1[(t + 2) * D + d], a2);
        a3 = fmaf(h.w, wnei_w1[(t + 3) * D + d], a3);
    }
    hid[d] = fmaxf(0.f, (a0 + a1) + (a2 + a3));
    __syncthreads();
    float b0 = wnei_b2[d], b1 = 0.f, b2 = 0.f, b3 = 0.f;
    const float4* gv = (const float4*)hid;
    #pragma unroll 4
    for (int t4 = 0; t4 < D / 4; ++t4) {
        float4 h = gv[t4];
        int t = t4 * 4;
        b0 = fmaf(h.x, wnei_w2[t * D + d], b0);
        b1 = fmaf(h.y, wnei_w2[(t + 1) * D + d], b1);
        b2 = fmaf(h.z, wnei_w2[(t + 2) * D + d], b2);
        b3 = fmaf(h.w, wnei_w2[(t + 3) * D + d], b3);
    }
    int idx = i * D + d;
    float C = (b0 + b1) + (b2 + b3) + self_c[idx];
    float og = outgate[idx];
    out[idx] = og;
    out[ND + idx] = og * tanhf(C);
    out[2 * ND + idx] = C;
}

extern "C" void kernel_launch(void* const* d_in, const int* in_sizes, int n_in,
                              void* d_out, int out_size, void* d_ws, size_t ws_size,
                              hipStream_t stream) {
    const float* corr    = (const float*)d_in[0];
    const int*   nei     = (const int*)d_in[1];
    const float* outg    = (const float*)d_in[3];
    const float* self_h  = (const float*)d_in[4];
    const float* self_c  = (const float*)d_in[5];
    const float* rel_w1  = (const float*)d_in[6];
    const float* rel_b1  = (const float*)d_in[7];
    const float* rel_w2  = (const float*)d_in[8];
    const float* rel_b2  = (const float*)d_in[9];
    const float* ngate_w = (const float*)d_in[10];
    const float* ngate_b = (const float*)d_in[11];
    const float* war_w   = (const float*)d_in[12];
    const float* war_b   = (const float*)d_in[13];
    const float* wnei_w1 = (const float*)d_in[14];
    const float* wnei_b1 = (const float*)d_in[15];
    const float* wnei_w2 = (const float*)d_in[16];
    const float* wnei_b2 = (const float*)d_in[17];

    float* ws      = (float*)d_ws;
    float* tt      = ws;                       // NN
    float* pos     = ws + NN;                  // NN
    float* A       = ws + 2 * NN;              // ND
    float* Bm      = ws + 2 * NN + ND;         // ND
    float* u       = ws + 2 * NN + 2 * ND;     // N
    float* v       = u + N;                    // N
    float* partial = v + N;                    // NCHUNK*ND
    float* rcache  = partial + NCHUNK * ND;    // NN*R (optional)
    size_t base_floats = (size_t)(2 * NN + 2 * ND + 2 * N + NCHUNK * ND);
    bool use_rc = ws_size >= (base_floats + (size_t)NN * R) * sizeof(float);
    float* out = (float*)d_out;

    precompute_kernel<<<N, 256, 0, stream>>>(self_h, ngate_w, war_w, A, Bm, u, v);
    tt_kernel<<<NN / TPB, 256, 0, stream>>>(corr, rel_w1, rel_b1, rel_w2, rel_b2,
                                            war_w, war_b, u, v, tt,
                                            use_rc ? rcache : nullptr);
    softmax_kernel<<<N, 256, 0, stream>>>(tt, nei, pos);
    dim3 ggrid(N, NCHUNK);
    if (use_rc) {
        gate_rc_kernel<<<ggrid, 256, 0, stream>>>(ngate_w, ngate_b, A, Bm, pos, self_h,
                                                  rcache, partial);
    } else {
        gate_norc_kernel<<<ggrid, 256, 0, stream>>>(corr, rel_w1, rel_b1, rel_w2, rel_b2,
                                                    ngate_w, ngate_b, A, Bm, pos, self_h,
                                                    partial);
    }
    final_kernel<<<N, 256, 0, stream>>>(partial, wnei_w1, wnei_b1, wnei_w2, wnei_b2,
                                        self_c, outg, out);
}

// Round 4
// 107.983 us; speedup vs baseline: 6.6557x; 1.7537x over previous
//
#include <hip/hip_runtime.h>
#include <hip/hip_bf16.h>
#include <math.h>

#define N 384
#define D 256
#define R 64
#define RELH 128
#define NN (N*N)
#define ND (N*D)
#define JCHUNK 64
#define NCHUNK (N / JCHUNK)   // 6
#define TPB 16                // legacy tt pairs per block (fallback)

typedef _Float16 f16x8 __attribute__((ext_vector_type(8)));
typedef float f32x4 __attribute__((ext_vector_type(4)));

// ---------------------------------------------------------------------------
// Precompute A[i,d] = h_i . ngate_w[64+t, d], B[j,d] = h_j . ngate_w[320+t, d]
// u[i] = h_i . war_w[64:320], v[j] = h_j . war_w[320:576]
// ---------------------------------------------------------------------------
__global__ void precompute_kernel(const float* __restrict__ self_h,
                                  const float* __restrict__ ngate_w,
                                  const float* __restrict__ war_w,
                                  float* __restrict__ A, float* __restrict__ B,
                                  float* __restrict__ u, float* __restrict__ v) {
    __shared__ float hrow[D];
    __shared__ float red[8];
    int i = blockIdx.x, d = threadIdx.x;
    hrow[d] = self_h[i * D + d];
    __syncthreads();
    float a0 = 0.f, a1 = 0.f, b0 = 0.f, b1 = 0.f;
    const float4* hv = (const float4*)hrow;
    #pragma unroll 4
    for (int t4 = 0; t4 < D / 4; ++t4) {
        float4 h = hv[t4];
        int t = t4 * 4;
        a0 = fmaf(h.x, ngate_w[(R + t) * D + d], a0);
        a1 = fmaf(h.y, ngate_w[(R + t + 1) * D + d], a1);
        a0 = fmaf(h.z, ngate_w[(R + t + 2) * D + d], a0);
        a1 = fmaf(h.w, ngate_w[(R + t + 3) * D + d], a1);
        b0 = fmaf(h.x, ngate_w[(R + D + t) * D + d], b0);
        b1 = fmaf(h.y, ngate_w[(R + D + t + 1) * D + d], b1);
        b0 = fmaf(h.z, ngate_w[(R + D + t + 2) * D + d], b0);
        b1 = fmaf(h.w, ngate_w[(R + D + t + 3) * D + d], b1);
    }
    A[i * D + d] = a0 + a1;
    B[i * D + d] = b0 + b1;
    float pu = hrow[d] * war_w[R + d];
    float pv = hrow[d] * war_w[R + D + d];
    for (int off = 32; off; off >>= 1) {
        pu += __shfl_down(pu, off);
        pv += __shfl_down(pv, off);
    }
    int lane = d & 63, w = d >> 6;
    if (lane == 0) { red[w] = pu; red[4 + w] = pv; }
    __syncthreads();
    if (d == 0) {
        u[i] = red[0] + red[1] + red[2] + red[3];
        v[i] = red[4] + red[5] + red[6] + red[7];
    }
}

// ---------------------------------------------------------------------------
// MFMA tt: r = relu(relu(corr@W1+b1)@W2+b2) via f16 MFMA (fp32 accum),
// rc[p*64+n] stored fp32; tt[p] = r.war_w[0:64] + u[i] + v[j] + war_b.
// One wave per 16 pairs, 4 tiles per wave; no LDS, no barriers.
// A-frag: row=lane&15, k=(lane>>4)*8+i ; B-frag: col=lane&15, same k;
// D: col=lane&15, row=(lane>>4)*4+reg.
// ---------------------------------------------------------------------------
__global__ __launch_bounds__(256, 2) void tt_mfma_kernel(
        const float* __restrict__ corr,
        const float* __restrict__ rel_w1, const float* __restrict__ rel_b1,
        const float* __restrict__ rel_w2, const float* __restrict__ rel_b2,
        const float* __restrict__ war_w, const float* __restrict__ war_b,
        const float* __restrict__ u, const float* __restrict__ v,
        float* __restrict__ tt, float* __restrict__ rc) {
    int tid = threadIdx.x;
    int w = tid >> 6, l = tid & 63;
    int lg = l >> 4;          // k-group 0..3
    int ln = l & 15;          // row/col within tile

    // hoist B fragments (W2): bfr[s][nt], k = s*32 + lg*8 + i, col = nt*16+ln
    f16x8 bfr[4][4];
    #pragma unroll
    for (int s = 0; s < 4; ++s)
        #pragma unroll
        for (int nt = 0; nt < 4; ++nt)
            #pragma unroll
            for (int i = 0; i < 8; ++i)
                bfr[s][nt][i] = (_Float16)rel_w2[(s * 32 + lg * 8 + i) * R + nt * 16 + ln];
    // hoist W1 / b1 at this lane's k slots
    float w10[4][8], w11[4][8], b1v[4][8];
    #pragma unroll
    for (int s = 0; s < 4; ++s)
        #pragma unroll
        for (int i = 0; i < 8; ++i) {
            int hk = s * 32 + lg * 8 + i;
            w10[s][i] = rel_w1[hk];
            w11[s][i] = rel_w1[RELH + hk];
            b1v[s][i] = rel_b1[hk];
        }
    float b2r[4], warw[4];
    #pragma unroll
    for (int nt = 0; nt < 4; ++nt) {
        b2r[nt]  = rel_b2[nt * 16 + ln];
        warw[nt] = war_w[nt * 16 + ln];
    }
    float wb = war_b[0];

    #pragma unroll
    for (int t = 0; t < 4; ++t) {
        int P0 = blockIdx.x * 256 + w * 64 + t * 16;
        float2 x = ((const float2*)corr)[P0 + ln];
        // A fragments: H1 row = ln's pair? No: row = lane&15 -> this lane's
        // A elements belong to pair P0+ln? A[m][k]: m=lane&15 -> pair P0+ln.
        f16x8 af[4];
        #pragma unroll
        for (int s = 0; s < 4; ++s)
            #pragma unroll
            for (int i = 0; i < 8; ++i) {
                float h = fmaxf(0.f, fmaf(x.y, w11[s][i], fmaf(x.x, w10[s][i], b1v[s][i])));
                af[s][i] = (_Float16)h;
            }
        f32x4 c[4];
        #pragma unroll
        for (int nt = 0; nt < 4; ++nt) c[nt] = (f32x4){0.f, 0.f, 0.f, 0.f};
        #pragma unroll
        for (int nt = 0; nt < 4; ++nt)
            #pragma unroll
            for (int s = 0; s < 4; ++s)
                c[nt] = __builtin_amdgcn_mfma_f32_16x16x32_f16(af[s], bfr[s][nt], c[nt], 0, 0, 0);
        // epilogue: relu(+b2), store rc, dot with war_w
        float tpart[4] = {0.f, 0.f, 0.f, 0.f};
        #pragma unroll
        for (int nt = 0; nt < 4; ++nt)
            #pragma unroll
            for (int reg = 0; reg < 4; ++reg) {
                float rv = fmaxf(0.f, c[nt][reg] + b2r[nt]);
                int m = lg * 4 + reg;
                rc[(size_t)(P0 + m) * R + nt * 16 + ln] = rv;
                tpart[reg] = fmaf(rv, warw[nt], tpart[reg]);
            }
        #pragma unroll
        for (int reg = 0; reg < 4; ++reg) {
            float tsum = tpart[reg];
            #pragma unroll
            for (int off = 8; off; off >>= 1) tsum += __shfl_xor(tsum, off, 16);
            tpart[reg] = tsum;
        }
        if (ln == 0) {
            #pragma unroll
            for (int reg = 0; reg < 4; ++reg) {
                int p = P0 + lg * 4 + reg;
                int i = p / N, j = p - i * N;
                tt[p] = tpart[reg] + u[i] + v[j] + wb;
            }
        }
    }
}

// ---------------------------------------------------------------------------
// Fallback VALU tt (only if workspace too small for rcache).
// ---------------------------------------------------------------------------
__global__ __launch_bounds__(256) void tt_valu_kernel(
        const float* __restrict__ corr,
        const float* __restrict__ rel_w1, const float* __restrict__ rel_b1,
        const float* __restrict__ rel_w2, const float* __restrict__ rel_b2,
        const float* __restrict__ war_w, const float* __restrict__ war_b,
        const float* __restrict__ u, const float* __restrict__ v,
        float* __restrict__ tt) {
    __shared__ __align__(16) float h1s[4][RELH];
    int tid = threadIdx.x, w = tid >> 6, l = tid & 63;
    float w1a0 = rel_w1[l],      w1a1 = rel_w1[RELH + l];
    float w1b0 = rel_w1[64 + l], w1b1 = rel_w1[RELH + 64 + l];
    float b1a = rel_b1[l], b1b = rel_b1[64 + l];
    float b2v = rel_b2[l], warw = war_w[l], wb = war_b[0];
    int pbase = blockIdx.x * TPB;
    #pragma unroll
    for (int it = 0; it < TPB / 4; ++it) {
        int p = pbase + it * 4 + w;
        int i = p / N, j = p - i * N;
        float2 x = *(const float2*)(corr + p * 2);
        h1s[w][l]      = fmaxf(0.f, fmaf(x.y, w1a1, fmaf(x.x, w1a0, b1a)));
        h1s[w][l + 64] = fmaxf(0.f, fmaf(x.y, w1b1, fmaf(x.x, w1b0, b1b)));
        float c0 = b2v, c1 = 0.f, c2 = 0.f, c3 = 0.f;
        const float4* hv = (const float4*)h1s[w];
        #pragma unroll
        for (int k4 = 0; k4 < RELH / 4; ++k4) {
            float4 h = hv[k4];
            c0 = fmaf(h.x, rel_w2[(k4 * 4 + 0) * R + l], c0);
            c1 = fmaf(h.y, rel_w2[(k4 * 4 + 1) * R + l], c1);
            c2 = fmaf(h.z, rel_w2[(k4 * 4 + 2) * R + l], c2);
            c3 = fmaf(h.w, rel_w2[(k4 * 4 + 3) * R + l], c3);
        }
        float rm = fmaxf(0.f, (c0 + c1) + (c2 + c3));
        float part = rm * warw;
        for (int off = 32; off; off >>= 1) part += __shfl_down(part, off);
        if (l == 0) tt[p] = part + u[i] + v[j] + wb;
    }
}

// ---------------------------------------------------------------------------
// Row softmax over valid entries (mask && tt != 0), zeros elsewhere.
// ---------------------------------------------------------------------------
__global__ void softmax_kernel(const float* __restrict__ tt,
                               const int* __restrict__ nei,
                               float* __restrict__ pos) {
    __shared__ float red[4];
    __shared__ float sM, sS;
    int i = blockIdx.x, tid = threadIdx.x;
    float tv[2]; bool valid[2];
    float m = -INFINITY;
    for (int s = 0; s < 2; ++s) {
        int j = tid + s * 256;
        valid[s] = false; tv[s] = 0.f;
        if (j < N) {
            float t = tt[i * N + j];
            bool va = (nei[i * N + j] > 0) && (t != 0.f);
            tv[s] = t; valid[s] = va;
            if (va) m = fmaxf(m, t);
        }
    }
    for (int off = 32; off; off >>= 1) m = fmaxf(m, __shfl_down(m, off));
    if ((tid & 63) == 0) red[tid >> 6] = m;
    __syncthreads();
    if (tid == 0) sM = fmaxf(fmaxf(red[0], red[1]), fmaxf(red[2], red[3]));
    __syncthreads();
    float M = sM;
    float e[2] = {0.f, 0.f};
    float sum = 0.f;
    if (M != -INFINITY) {
        for (int s = 0; s < 2; ++s)
            if (valid[s]) { e[s] = expf(tv[s] - M); sum += e[s]; }
    }
    for (int off = 32; off; off >>= 1) sum += __shfl_down(sum, off);
    if ((tid & 63) == 0) red[tid >> 6] = sum;
    __syncthreads();
    if (tid == 0) sS = red[0] + red[1] + red[2] + red[3];
    __syncthreads();
    float denom = sS;
    for (int s = 0; s < 2; ++s) {
        int j = tid + s * 256;
        if (j < N) pos[i * N + j] = (valid[s] && denom > 0.f) ? e[s] / denom : 0.f;
    }
}

// ---------------------------------------------------------------------------
// gate (rcache path): ngate_w[0:64, tid] hoisted into 64 VGPRs; whole
// 64-j chunk of r staged into LDS with one bulk copy + one barrier;
// compacted active-j list via ballot; unconditional inner loop.
// ---------------------------------------------------------------------------
__global__ __launch_bounds__(256) void gate_rc_kernel(
        const float* __restrict__ ngate_w, const float* __restrict__ ngate_b,
        const float* __restrict__ A, const float* __restrict__ Bm,
        const float* __restrict__ pos, const float* __restrict__ self_h,
        const float* __restrict__ rcache, float* __restrict__ partial) {
    __shared__ __align__(16) float rsall[JCHUNK][R];   // 16 KB
    __shared__ float posv[JCHUNK];
    __shared__ int jlist[JCHUNK];
    __shared__ int scnt;
    int i = blockIdx.x, tid = threadIdx.x;
    int jbase = blockIdx.y * JCHUNK;
    float wreg[R];
    #pragma unroll
    for (int m = 0; m < R; ++m) wreg[m] = ngate_w[m * D + tid];
    float base = ngate_b[tid] + A[i * D + tid];
    const float4* src = (const float4*)(rcache + (size_t)(i * N + jbase) * R);
    float4* dst = (float4*)rsall;
    #pragma unroll
    for (int s = 0; s < 4; ++s) dst[tid + s * 256] = src[tid + s * 256];
    if (tid < JCHUNK) {
        float pv = pos[i * N + jbase + tid];
        posv[tid] = pv;
        bool act = pv != 0.f;
        unsigned long long mask = __ballot(act);
        int pre = __popcll(mask & ((1ull << tid) - 1));
        if (act) jlist[pre] = tid;
        if (tid == 0) scnt = (int)__popcll(mask);
    }
    __syncthreads();
    int cnt = scnt;
    float acc = 0.f;
    for (int c = 0; c < cnt; ++c) {
        int j = jlist[c];
        int jj = jbase + j;
        float wt = posv[j];
        float bmv = Bm[jj * D + tid];
        float hv  = self_h[jj * D + tid];
        const float4* rv = (const float4*)rsall[j];
        float l0 = 0.f, l1 = 0.f, l2 = 0.f, l3 = 0.f;
        #pragma unroll
        for (int m4 = 0; m4 < R / 4; ++m4) {
            float4 r4 = rv[m4];
            l0 = fmaf(r4.x, wreg[m4 * 4 + 0], l0);
            l1 = fmaf(r4.y, wreg[m4 * 4 + 1], l1);
            l2 = fmaf(r4.z, wreg[m4 * 4 + 2], l2);
            l3 = fmaf(r4.w, wreg[m4 * 4 + 3], l3);
        }
        float logit = base + bmv + ((l0 + l1) + (l2 + l3));
        float g = 1.f / (1.f + expf(-logit));
        acc = fmaf(wt * hv, g, acc);
    }
    partial[(blockIdx.y * N + i) * D + tid] = acc;
}

// ---------------------------------------------------------------------------
// Fallback gate (no rcache): recompute rel MLP per active pair.
// ---------------------------------------------------------------------------
__global__ void gate_norc_kernel(const float* __restrict__ corr,
                            const float* __restrict__ rel_w1, const float* __restrict__ rel_b1,
                            const float* __restrict__ rel_w2, const float* __restrict__ rel_b2,
                            const float* __restrict__ ngate_w, const float* __restrict__ ngate_b,
                            const float* __restrict__ A, const float* __restrict__ Bm,
                            const float* __restrict__ pos, const float* __restrict__ self_h,
                            float* __restrict__ partial) {
    __shared__ __align__(16) float h1[4][RELH];
    __shared__ __align__(16) float rs[4][R];
    __shared__ float wsh[4];
    int i = blockIdx.x, tid = threadIdx.x;
    int jbase = blockIdx.y * JCHUNK;
    int w = tid >> 6, l = tid & 63;
    ((float*)rs)[tid] = 0.f;
    float base = ngate_b[tid] + A[i * D + tid];
    float acc = 0.f;
    for (int j0 = jbase; j0 < jbase + JCHUNK; j0 += 4) {
        int j = j0 + w;
        int p = i * N + j;
        float wt = pos[p];
        if (l == 0) wsh[w] = wt;
        if (wt != 0.f) {
            float x0 = corr[p * 2], x1 = corr[p * 2 + 1];
            h1[w][l]      = fmaxf(0.f, fmaf(x1, rel_w1[RELH + l],      fmaf(x0, rel_w1[l],      rel_b1[l])));
            h1[w][l + 64] = fmaxf(0.f, fmaf(x1, rel_w1[RELH + l + 64], fmaf(x0, rel_w1[l + 64], rel_b1[l + 64])));
        }
        __syncthreads();
        if (wsh[w] != 0.f) {
            float c0 = rel_b2[l], c1 = 0.f, c2 = 0.f, c3 = 0.f;
            const float4* hv = (const float4*)h1[w];
            #pragma unroll 8
            for (int k4 = 0; k4 < RELH / 4; ++k4) {
                float4 h = hv[k4];
                int k = k4 * 4;
                c0 = fmaf(h.x, rel_w2[k * R + l], c0);
                c1 = fmaf(h.y, rel_w2[(k + 1) * R + l], c1);
                c2 = fmaf(h.z, rel_w2[(k + 2) * R + l], c2);
                c3 = fmaf(h.w, rel_w2[(k + 3) * R + l], c3);
            }
            rs[w][l] = fmaxf(0.f, (c0 + c1) + (c2 + c3));
        }
        __syncthreads();
        #pragma unroll
        for (int ww = 0; ww < 4; ++ww) {
            float wtj = wsh[ww];
            if (wtj != 0.f) {
                int jj = j0 + ww;
                const float4* rv = (const float4*)rs[ww];
                float l0 = 0.f, l1 = 0.f, l2 = 0.f, l3 = 0.f;
                #pragma unroll 4
                for (int m4 = 0; m4 < R / 4; ++m4) {
                    float4 r4 = rv[m4];
                    int m = m4 * 4;
                    l0 = fmaf(r4.x, ngate_w[m * D + tid], l0);
                    l1 = fmaf(r4.y, ngate_w[(m + 1) * D + tid], l1);
                    l2 = fmaf(r4.z, ngate_w[(m + 2) * D + tid], l2);
                    l3 = fmaf(r4.w, ngate_w[(m + 3) * D + tid], l3);
                }
                float logit = base + Bm[jj * D + tid] + ((l0 + l1) + (l2 + l3));
                float g = 1.f / (1.f + expf(-logit));
                acc = fmaf(wtj * self_h[jj * D + tid], g, acc);
            }
        }
        __syncthreads();
    }
    partial[(blockIdx.y * N + i) * D + tid] = acc;
}

// ---------------------------------------------------------------------------
// hsum = sum of partials; hidden = relu(hsum@W1+b1); out2 = hidden@W2+b2;
// C = out2 + self_c; H_out = outgate * tanh(C); outputs = (outgate, H_out, C)
// ---------------------------------------------------------------------------
__global__ void final_kernel(const float* __restrict__ partial,
                             const float* __restrict__ wnei_w1, const float* __restrict__ wnei_b1,
                             const float* __restrict__ wnei_w2, const float* __restrict__ wnei_b2,
                             const float* __restrict__ self_c, const float* __restrict__ outgate,
                             float* __restrict__ out) {
    __shared__ __align__(16) float hs[D];
    __shared__ __align__(16) float hid[D];
    int i = blockIdx.x, d = threadIdx.x;
    float s = 0.f;
    #pragma unroll
    for (int c = 0; c < NCHUNK; ++c) s += partial[(c * N + i) * D + d];
    hs[d] = s;
    __syncthreads();
    float a0 = wnei_b1[d], a1 = 0.f, a2 = 0.f, a3 = 0.f;
    const float4* hv = (const float4*)hs;
    #pragma unroll 4
    for (int t4 = 0; t4 < D / 4; ++t4) {
        float4 h = hv[t4];
        int t = t4 * 4;
        a0 = fmaf(h.x, wnei_w1[t * D + d], a0);
        a1 = fmaf(h.y, wnei_w1[(t + 1) * D + d], a1);
        a2 = fmaf(h.z, wnei_w1[(t + 2) * D + d], a2);
        a3 = fmaf(h.w, wnei_w1[(t + 3) * D + d], a3);
    }
    hid[d] = fmaxf(0.f, (a0 + a1) + (a2 + a3));
    __syncthreads();
    float b0 = wnei_b2[d], b1 = 0.f, b2 = 0.f, b3 = 0.f;
    const float4* gv = (const float4*)hid;
    #pragma unroll 4
    for (int t4 = 0; t4 < D / 4; ++t4) {
        float4 h = gv[t4];
        int t = t4 * 4;
        b0 = fmaf(h.x, wnei_w2[t * D + d], b0);
        b1 = fmaf(h.y, wnei_w2[(t + 1) * D + d], b1);
        b2 = fmaf(h.z, wnei_w2[(t + 2) * D + d], b2);
        b3 = fmaf(h.w, wnei_w2[(t + 3) * D + d], b3);
    }
    int idx = i * D + d;
    float C = (b0 + b1) + (b2 + b3) + self_c[idx];
    float og = outgate[idx];
    out[idx] = og;
    out[ND + idx] = og * tanhf(C);
    out[2 * ND + idx] = C;
}

extern "C" void kernel_launch(void* const* d_in, const int* in_sizes, int n_in,
                              void* d_out, int out_size, void* d_ws, size_t ws_size,
                              hipStream_t stream) {
    const float* corr    = (const float*)d_in[0];
    const int*   nei     = (const int*)d_in[1];
    const float* outg    = (const float*)d_in[3];
    const float* self_h  = (const float*)d_in[4];
    const float* self_c  = (const float*)d_in[5];
    const float* rel_w1  = (const float*)d_in[6];
    const float* rel_b1  = (const float*)d_in[7];
    const float* rel_w2  = (const float*)d_in[8];
    const float* rel_b2  = (const float*)d_in[9];
    const float* ngate_w = (const float*)d_in[10];
    const float* ngate_b = (const float*)d_in[11];
    const float* war_w   = (const float*)d_in[12];
    const float* war_b   = (const float*)d_in[13];
    const float* wnei_w1 = (const float*)d_in[14];
    const float* wnei_b1 = (const float*)d_in[15];
    const float* wnei_w2 = (const float*)d_in[16];
    const float* wnei_b2 = (const float*)d_in[17];

    float* ws      = (float*)d_ws;
    float* tt      = ws;                       // NN
    float* pos     = ws + NN;                  // NN
    float* A       = ws + 2 * NN;              // ND
    float* Bm      = ws + 2 * NN + ND;         // ND
    float* u       = ws + 2 * NN + 2 * ND;     // N
    float* v       = u + N;                    // N
    float* partial = v + N;                    // NCHUNK*ND
    float* rcache  = partial + NCHUNK * ND;    // NN*R (optional)
    size_t base_floats = (size_t)(2 * NN + 2 * ND + 2 * N + NCHUNK * ND);
    bool use_rc = ws_size >= (base_floats + (size_t)NN * R) * sizeof(float);
    float* out = (float*)d_out;

    precompute_kernel<<<N, 256, 0, stream>>>(self_h, ngate_w, war_w, A, Bm, u, v);
    if (use_rc) {
        tt_mfma_kernel<<<NN / 256, 256, 0, stream>>>(corr, rel_w1, rel_b1, rel_w2, rel_b2,
                                                     war_w, war_b, u, v, tt, rcache);
    } else {
        tt_valu_kernel<<<NN / TPB, 256, 0, stream>>>(corr, rel_w1, rel_b1, rel_w2, rel_b2,
                                                     war_w, war_b, u, v, tt);
    }
    softmax_kernel<<<N, 256, 0, stream>>>(tt, nei, pos);
    dim3 ggrid(N, NCHUNK);
    if (use_rc) {
        gate_rc_kernel<<<ggrid, 256, 0, stream>>>(ngate_w, ngate_b, A, Bm, pos, self_h,
                                                  rcache, partial);
    } else {
        gate_norc_kernel<<<ggrid, 256, 0, stream>>>(corr, rel_w1, rel_b1, rel_w2, rel_b2,
                                                    ngate_w, ngate_b, A, Bm, pos, self_h,
                                                    partial);
    }
    final_kernel<<<N, 256, 0, stream>>>(partial, wnei_w1, wnei_b1, wnei_w2, wnei_b2,
                                        self_c, outg, out);
}

// Round 5
// 90.178 us; speedup vs baseline: 7.9698x; 1.1974x over previous
//
#include <hip/hip_runtime.h>
#include <hip/hip_bf16.h>
#include <math.h>

#define N 384
#define D 256
#define R 64
#define RELH 128
#define NN (N*N)
#define ND (N*D)
#define JCHUNK 64
#define NCHUNK (N / JCHUNK)   // 6
#define TPB 16                // legacy tt pairs per block (fallback)

typedef _Float16 f16x8 __attribute__((ext_vector_type(8)));
typedef float f32x4 __attribute__((ext_vector_type(4)));

// ---------------------------------------------------------------------------
// Precompute A[i,d] = h_i . ngate_w[64+t, d], B[j,d] = h_j . ngate_w[320+t, d]
// u[i] = h_i . war_w[64:320], v[j] = h_j . war_w[320:576]
// ---------------------------------------------------------------------------
__global__ void precompute_kernel(const float* __restrict__ self_h,
                                  const float* __restrict__ ngate_w,
                                  const float* __restrict__ war_w,
                                  float* __restrict__ A, float* __restrict__ B,
                                  float* __restrict__ u, float* __restrict__ v) {
    __shared__ float hrow[D];
    __shared__ float red[8];
    int i = blockIdx.x, d = threadIdx.x;
    hrow[d] = self_h[i * D + d];
    __syncthreads();
    float a0 = 0.f, a1 = 0.f, b0 = 0.f, b1 = 0.f;
    const float4* hv = (const float4*)hrow;
    #pragma unroll 4
    for (int t4 = 0; t4 < D / 4; ++t4) {
        float4 h = hv[t4];
        int t = t4 * 4;
        a0 = fmaf(h.x, ngate_w[(R + t) * D + d], a0);
        a1 = fmaf(h.y, ngate_w[(R + t + 1) * D + d], a1);
        a0 = fmaf(h.z, ngate_w[(R + t + 2) * D + d], a0);
        a1 = fmaf(h.w, ngate_w[(R + t + 3) * D + d], a1);
        b0 = fmaf(h.x, ngate_w[(R + D + t) * D + d], b0);
        b1 = fmaf(h.y, ngate_w[(R + D + t + 1) * D + d], b1);
        b0 = fmaf(h.z, ngate_w[(R + D + t + 2) * D + d], b0);
        b1 = fmaf(h.w, ngate_w[(R + D + t + 3) * D + d], b1);
    }
    A[i * D + d] = a0 + a1;
    B[i * D + d] = b0 + b1;
    float pu = hrow[d] * war_w[R + d];
    float pv = hrow[d] * war_w[R + D + d];
    for (int off = 32; off; off >>= 1) {
        pu += __shfl_down(pu, off);
        pv += __shfl_down(pv, off);
    }
    int lane = d & 63, w = d >> 6;
    if (lane == 0) { red[w] = pu; red[4 + w] = pv; }
    __syncthreads();
    if (d == 0) {
        u[i] = red[0] + red[1] + red[2] + red[3];
        v[i] = red[4] + red[5] + red[6] + red[7];
    }
}

// ---------------------------------------------------------------------------
// Build fp16 B-fragment buffer for ngate_w[0:64, :], fragment-ordered:
// wf[((s*16 + t)*64 + lane)*8 + i] = ngate_w[(s*32 + (lane>>4)*8 + i)*D + t*16 + (lane&15)]
// 32 blocks (s,t) x 64 threads.
// ---------------------------------------------------------------------------
__global__ void wfrag_kernel(const float* __restrict__ ngate_w,
                             _Float16* __restrict__ wf) {
    int s = blockIdx.x >> 4, t = blockIdx.x & 15;
    int lane = threadIdx.x;
    int lg = lane >> 4, ln = lane & 15;
    #pragma unroll
    for (int i = 0; i < 8; ++i) {
        float w = ngate_w[(s * 32 + lg * 8 + i) * D + t * 16 + ln];
        wf[((size_t)(s * 16 + t) * 64 + lane) * 8 + i] = (_Float16)w;
    }
}

// ---------------------------------------------------------------------------
// MFMA tt: r = relu(relu(corr@W1+b1)@W2+b2) via f16 MFMA (fp32 accum),
// rc stored FP16; tt[p] = r.war_w[0:64] + u[i] + v[j] + war_b.
// One wave per 64 pairs (4 tiles); no LDS, no barriers.
// A-frag: row=lane&15, k=(lane>>4)*8+i ; B-frag: col=lane&15, same k;
// D: col=lane&15, row=(lane>>4)*4+reg.
// ---------------------------------------------------------------------------
__global__ __launch_bounds__(256, 2) void tt_mfma_kernel(
        const float* __restrict__ corr,
        const float* __restrict__ rel_w1, const float* __restrict__ rel_b1,
        const float* __restrict__ rel_w2, const float* __restrict__ rel_b2,
        const float* __restrict__ war_w, const float* __restrict__ war_b,
        const float* __restrict__ u, const float* __restrict__ v,
        float* __restrict__ tt, _Float16* __restrict__ rc) {
    int tid = threadIdx.x;
    int w = tid >> 6, l = tid & 63;
    int lg = l >> 4;          // k-group 0..3
    int ln = l & 15;          // row/col within tile

    // hoist B fragments (W2): bfr[s][nt], k = s*32 + lg*8 + i, col = nt*16+ln
    f16x8 bfr[4][4];
    #pragma unroll
    for (int s = 0; s < 4; ++s)
        #pragma unroll
        for (int nt = 0; nt < 4; ++nt)
            #pragma unroll
            for (int i = 0; i < 8; ++i)
                bfr[s][nt][i] = (_Float16)rel_w2[(s * 32 + lg * 8 + i) * R + nt * 16 + ln];
    // hoist W1 / b1 at this lane's k slots
    float w10[4][8], w11[4][8], b1v[4][8];
    #pragma unroll
    for (int s = 0; s < 4; ++s)
        #pragma unroll
        for (int i = 0; i < 8; ++i) {
            int hk = s * 32 + lg * 8 + i;
            w10[s][i] = rel_w1[hk];
            w11[s][i] = rel_w1[RELH + hk];
            b1v[s][i] = rel_b1[hk];
        }
    float b2r[4], warw[4];
    #pragma unroll
    for (int nt = 0; nt < 4; ++nt) {
        b2r[nt]  = rel_b2[nt * 16 + ln];
        warw[nt] = war_w[nt * 16 + ln];
    }
    float wb = war_b[0];

    #pragma unroll
    for (int t = 0; t < 4; ++t) {
        int P0 = blockIdx.x * 256 + w * 64 + t * 16;
        float2 x = ((const float2*)corr)[P0 + ln];
        f16x8 af[4];
        #pragma unroll
        for (int s = 0; s < 4; ++s)
            #pragma unroll
            for (int i = 0; i < 8; ++i) {
                float h = fmaxf(0.f, fmaf(x.y, w11[s][i], fmaf(x.x, w10[s][i], b1v[s][i])));
                af[s][i] = (_Float16)h;
            }
        f32x4 c[4];
        #pragma unroll
        for (int nt = 0; nt < 4; ++nt) c[nt] = (f32x4){0.f, 0.f, 0.f, 0.f};
        #pragma unroll
        for (int nt = 0; nt < 4; ++nt)
            #pragma unroll
            for (int s = 0; s < 4; ++s)
                c[nt] = __builtin_amdgcn_mfma_f32_16x16x32_f16(af[s], bfr[s][nt], c[nt], 0, 0, 0);
        // epilogue: relu(+b2), store rc fp16, dot with war_w
        float tpart[4] = {0.f, 0.f, 0.f, 0.f};
        #pragma unroll
        for (int nt = 0; nt < 4; ++nt)
            #pragma unroll
            for (int reg = 0; reg < 4; ++reg) {
                float rv = fmaxf(0.f, c[nt][reg] + b2r[nt]);
                int m = lg * 4 + reg;
                rc[(size_t)(P0 + m) * R + nt * 16 + ln] = (_Float16)rv;
                tpart[reg] = fmaf(rv, warw[nt], tpart[reg]);
            }
        #pragma unroll
        for (int reg = 0; reg < 4; ++reg) {
            float tsum = tpart[reg];
            #pragma unroll
            for (int off = 8; off; off >>= 1) tsum += __shfl_xor(tsum, off, 16);
            tpart[reg] = tsum;
        }
        if (ln == 0) {
            #pragma unroll
            for (int reg = 0; reg < 4; ++reg) {
                int p = P0 + lg * 4 + reg;
                int i = p / N, j = p - i * N;
                tt[p] = tpart[reg] + u[i] + v[j] + wb;
            }
        }
    }
}

// ---------------------------------------------------------------------------
// Fallback VALU tt (only if workspace too small for rcache).
// ---------------------------------------------------------------------------
__global__ __launch_bounds__(256) void tt_valu_kernel(
        const float* __restrict__ corr,
        const float* __restrict__ rel_w1, const float* __restrict__ rel_b1,
        const float* __restrict__ rel_w2, const float* __restrict__ rel_b2,
        const float* __restrict__ war_w, const float* __restrict__ war_b,
        const float* __restrict__ u, const float* __restrict__ v,
        float* __restrict__ tt) {
    __shared__ __align__(16) float h1s[4][RELH];
    int tid = threadIdx.x, w = tid >> 6, l = tid & 63;
    float w1a0 = rel_w1[l],      w1a1 = rel_w1[RELH + l];
    float w1b0 = rel_w1[64 + l], w1b1 = rel_w1[RELH + 64 + l];
    float b1a = rel_b1[l], b1b = rel_b1[64 + l];
    float b2v = rel_b2[l], warw = war_w[l], wb = war_b[0];
    int pbase = blockIdx.x * TPB;
    #pragma unroll
    for (int it = 0; it < TPB / 4; ++it) {
        int p = pbase + it * 4 + w;
        int i = p / N, j = p - i * N;
        float2 x = *(const float2*)(corr + p * 2);
        h1s[w][l]      = fmaxf(0.f, fmaf(x.y, w1a1, fmaf(x.x, w1a0, b1a)));
        h1s[w][l + 64] = fmaxf(0.f, fmaf(x.y, w1b1, fmaf(x.x, w1b0, b1b)));
        float c0 = b2v, c1 = 0.f, c2 = 0.f, c3 = 0.f;
        const float4* hv = (const float4*)h1s[w];
        #pragma unroll
        for (int k4 = 0; k4 < RELH / 4; ++k4) {
            float4 h = hv[k4];
            c0 = fmaf(h.x, rel_w2[(k4 * 4 + 0) * R + l], c0);
            c1 = fmaf(h.y, rel_w2[(k4 * 4 + 1) * R + l], c1);
            c2 = fmaf(h.z, rel_w2[(k4 * 4 + 2) * R + l], c2);
            c3 = fmaf(h.w, rel_w2[(k4 * 4 + 3) * R + l], c3);
        }
        float rm = fmaxf(0.f, (c0 + c1) + (c2 + c3));
        float part = rm * warw;
        for (int off = 32; off; off >>= 1) part += __shfl_down(part, off);
        if (l == 0) tt[p] = part + u[i] + v[j] + wb;
    }
}

// ---------------------------------------------------------------------------
// Row softmax over valid entries (mask && tt != 0), zeros elsewhere.
// ---------------------------------------------------------------------------
__global__ void softmax_kernel(const float* __restrict__ tt,
                               const int* __restrict__ nei,
                               float* __restrict__ pos) {
    __shared__ float red[4];
    __shared__ float sM, sS;
    int i = blockIdx.x, tid = threadIdx.x;
    float tv[2]; bool valid[2];
    float m = -INFINITY;
    for (int s = 0; s < 2; ++s) {
        int j = tid + s * 256;
        valid[s] = false; tv[s] = 0.f;
        if (j < N) {
            float t = tt[i * N + j];
            bool va = (nei[i * N + j] > 0) && (t != 0.f);
            tv[s] = t; valid[s] = va;
            if (va) m = fmaxf(m, t);
        }
    }
    for (int off = 32; off; off >>= 1) m = fmaxf(m, __shfl_down(m, off));
    if ((tid & 63) == 0) red[tid >> 6] = m;
    __syncthreads();
    if (tid == 0) sM = fmaxf(fmaxf(red[0], red[1]), fmaxf(red[2], red[3]));
    __syncthreads();
    float M = sM;
    float e[2] = {0.f, 0.f};
    float sum = 0.f;
    if (M != -INFINITY) {
        for (int s = 0; s < 2; ++s)
            if (valid[s]) { e[s] = expf(tv[s] - M); sum += e[s]; }
    }
    for (int off = 32; off; off >>= 1) sum += __shfl_down(sum, off);
    if ((tid & 63) == 0) red[tid >> 6] = sum;
    __syncthreads();
    if (tid == 0) sS = red[0] + red[1] + red[2] + red[3];
    __syncthreads();
    float denom = sS;
    for (int s = 0; s < 2; ++s) {
        int j = tid + s * 256;
        if (j < N) pos[i * N + j] = (valid[s] && denom > 0.f) ? e[s] / denom : 0.f;
    }
}

// ---------------------------------------------------------------------------
// MFMA gate: per (i, jchunk) block, logits L[64j x 256d] = r @ ngate_w[0:64,:]
// via f16 MFMA; then acc[d] += pos[j]*h[j,d]*sigmoid(L + base[d] + Bm[j,d]).
// pos==0 rows contribute exactly 0 -> branch-free, no compaction needed.
// 4 waves x 4 dtiles; A-frags from fp16 rcache; B-frags from wf buffer.
// ---------------------------------------------------------------------------
__global__ __launch_bounds__(256, 2) void gate_mfma_kernel(
        const _Float16* __restrict__ rc16, const _Float16* __restrict__ wf,
        const float* __restrict__ ngate_b, const float* __restrict__ A,
        const float* __restrict__ Bm, const float* __restrict__ pos,
        const float* __restrict__ self_h, float* __restrict__ partial) {
    int i = blockIdx.x;
    int jbase = blockIdx.y * JCHUNK;
    int tid = threadIdx.x, w = tid >> 6, l = tid & 63;
    int lg = l >> 4, ln = l & 15;

    // B fragments: dtiles w*4 .. w*4+3
    f16x8 bf[2][4];
    #pragma unroll
    for (int s = 0; s < 2; ++s)
        #pragma unroll
        for (int t = 0; t < 4; ++t)
            bf[s][t] = *(const f16x8*)&wf[((size_t)(s * 16 + w * 4 + t) * 64 + l) * 8];

    // A fragments: af[jt][s], row = jbase + jt*16 + ln, k = s*32 + lg*8 + i
    f16x8 af[4][2];
    #pragma unroll
    for (int jt = 0; jt < 4; ++jt)
        #pragma unroll
        for (int s = 0; s < 2; ++s)
            af[jt][s] = *(const f16x8*)&rc16[(size_t)(i * N + jbase + jt * 16 + ln) * R + s * 32 + lg * 8];

    float based[4];
    #pragma unroll
    for (int t = 0; t < 4; ++t) {
        int d = w * 64 + t * 16 + ln;
        based[t] = ngate_b[d] + A[i * D + d];
    }

    float acc[4] = {0.f, 0.f, 0.f, 0.f};
    #pragma unroll
    for (int jt = 0; jt < 4; ++jt) {
        f32x4 c[4];
        #pragma unroll
        for (int t = 0; t < 4; ++t) c[t] = (f32x4){0.f, 0.f, 0.f, 0.f};
        #pragma unroll
        for (int t = 0; t < 4; ++t)
            #pragma unroll
            for (int s = 0; s < 2; ++s)
                c[t] = __builtin_amdgcn_mfma_f32_16x16x32_f16(af[jt][s], bf[s][t], c[t], 0, 0, 0);
        #pragma unroll
        for (int reg = 0; reg < 4; ++reg) {
            int jj = jbase + jt * 16 + lg * 4 + reg;
            float pj = pos[i * N + jj];
            #pragma unroll
            for (int t = 0; t < 4; ++t) {
                int d = w * 64 + t * 16 + ln;
                float bm = Bm[jj * D + d];
                float h  = self_h[jj * D + d];
                float logit = c[t][reg] + based[t] + bm;
                float g = 1.f / (1.f + expf(-logit));
                acc[t] = fmaf(pj * h, g, acc[t]);
            }
        }
    }
    // reduce over the 4 lane-groups (different j subsets, same d)
    #pragma unroll
    for (int t = 0; t < 4; ++t) {
        float a = acc[t];
        a += __shfl_xor(a, 16);
        a += __shfl_xor(a, 32);
        acc[t] = a;
    }
    if (lg == 0) {
        #pragma unroll
        for (int t = 0; t < 4; ++t)
            partial[(size_t)(blockIdx.y * N + i) * D + w * 64 + t * 16 + ln] = acc[t];
    }
}

// ---------------------------------------------------------------------------
// Fallback gate (no rcache): recompute rel MLP per active pair.
// ---------------------------------------------------------------------------
__global__ void gate_norc_kernel(const float* __restrict__ corr,
                            const float* __restrict__ rel_w1, const float* __restrict__ rel_b1,
                            const float* __restrict__ rel_w2, const float* __restrict__ rel_b2,
                            const float* __restrict__ ngate_w, const float* __restrict__ ngate_b,
                            const float* __restrict__ A, const float* __restrict__ Bm,
                            const float* __restrict__ pos, const float* __restrict__ self_h,
                            float* __restrict__ partial) {
    __shared__ __align__(16) float h1[4][RELH];
    __shared__ __align__(16) float rs[4][R];
    __shared__ float wsh[4];
    int i = blockIdx.x, tid = threadIdx.x;
    int jbase = blockIdx.y * JCHUNK;
    int w = tid >> 6, l = tid & 63;
    ((float*)rs)[tid] = 0.f;
    float base = ngate_b[tid] + A[i * D + tid];
    float acc = 0.f;
    for (int j0 = jbase; j0 < jbase + JCHUNK; j0 += 4) {
        int j = j0 + w;
        int p = i * N + j;
        float wt = pos[p];
        if (l == 0) wsh[w] = wt;
        if (wt != 0.f) {
            float x0 = corr[p * 2], x1 = corr[p * 2 + 1];
            h1[w][l]      = fmaxf(0.f, fmaf(x1, rel_w1[RELH + l],      fmaf(x0, rel_w1[l],      rel_b1[l])));
            h1[w][l + 64] = fmaxf(0.f, fmaf(x1, rel_w1[RELH + l + 64], fmaf(x0, rel_w1[l + 64], rel_b1[l + 64])));
        }
        __syncthreads();
        if (wsh[w] != 0.f) {
            float c0 = rel_b2[l], c1 = 0.f, c2 = 0.f, c3 = 0.f;
            const float4* hv = (const float4*)h1[w];
            #pragma unroll 8
            for (int k4 = 0; k4 < RELH / 4; ++k4) {
                float4 h = hv[k4];
                int k = k4 * 4;
                c0 = fmaf(h.x, rel_w2[k * R + l], c0);
                c1 = fmaf(h.y, rel_w2[(k + 1) * R + l], c1);
                c2 = fmaf(h.z, rel_w2[(k + 2) * R + l], c2);
                c3 = fmaf(h.w, rel_w2[(k + 3) * R + l], c3);
            }
            rs[w][l] = fmaxf(0.f, (c0 + c1) + (c2 + c3));
        }
        __syncthreads();
        #pragma unroll
        for (int ww = 0; ww < 4; ++ww) {
            float wtj = wsh[ww];
            if (wtj != 0.f) {
                int jj = j0 + ww;
                const float4* rv = (const float4*)rs[ww];
                float l0 = 0.f, l1 = 0.f, l2 = 0.f, l3 = 0.f;
                #pragma unroll 4
                for (int m4 = 0; m4 < R / 4; ++m4) {
                    float4 r4 = rv[m4];
                    int m = m4 * 4;
                    l0 = fmaf(r4.x, ngate_w[m * D + tid], l0);
                    l1 = fmaf(r4.y, ngate_w[(m + 1) * D + tid], l1);
                    l2 = fmaf(r4.z, ngate_w[(m + 2) * D + tid], l2);
                    l3 = fmaf(r4.w, ngate_w[(m + 3) * D + tid], l3);
                }
                float logit = base + Bm[jj * D + tid] + ((l0 + l1) + (l2 + l3));
                float g = 1.f / (1.f + expf(-logit));
                acc = fmaf(wtj * self_h[jj * D + tid], g, acc);
            }
        }
        __syncthreads();
    }
    partial[(blockIdx.y * N + i) * D + tid] = acc;
}

// ---------------------------------------------------------------------------
// hsum = sum of partials; hidden = relu(hsum@W1+b1); out2 = hidden@W2+b2;
// C = out2 + self_c; H_out = outgate * tanh(C); outputs = (outgate, H_out, C)
// ---------------------------------------------------------------------------
__global__ void final_kernel(const float* __restrict__ partial,
                             const float* __restrict__ wnei_w1, const float* __restrict__ wnei_b1,
                             const float* __restrict__ wnei_w2, const float* __restrict__ wnei_b2,
                             const float* __restrict__ self_c, const float* __restrict__ outgate,
                             float* __restrict__ out) {
    __shared__ __align__(16) float hs[D];
    __shared__ __align__(16) float hid[D];
    int i = blockIdx.x, d = threadIdx.x;
    float s = 0.f;
    #pragma unroll
    for (int c = 0; c < NCHUNK; ++c) s += partial[(c * N + i) * D + d];
    hs[d] = s;
    __syncthreads();
    float a0 = wnei_b1[d], a1 = 0.f, a2 = 0.f, a3 = 0.f;
    const float4* hv = (const float4*)hs;
    #pragma unroll 4
    for (int t4 = 0; t4 < D / 4; ++t4) {
        float4 h = hv[t4];
        int t = t4 * 4;
        a0 = fmaf(h.x, wnei_w1[t * D + d], a0);
        a1 = fmaf(h.y, wnei_w1[(t + 1) * D + d], a1);
        a2 = fmaf(h.z, wnei_w1[(t + 2) * D + d], a2);
        a3 = fmaf(h.w, wnei_w1[(t + 3) * D + d], a3);
    }
    hid[d] = fmaxf(0.f, (a0 + a1) + (a2 + a3));
    __syncthreads();
    float b0 = wnei_b2[d], b1 = 0.f, b2 = 0.f, b3 = 0.f;
    const float4* gv = (const float4*)hid;
    #pragma unroll 4
    for (int t4 = 0; t4 < D / 4; ++t4) {
        float4 h = gv[t4];
        int t = t4 * 4;
        b0 = fmaf(h.x, wnei_w2[t * D + d], b0);
        b1 = fmaf(h.y, wnei_w2[(t + 1) * D + d], b1);
        b2 = fmaf(h.z, wnei_w2[(t + 2) * D + d], b2);
        b3 = fmaf(h.w, wnei_w2[(t + 3) * D + d], b3);
    }
    int idx = i * D + d;
    float C = (b0 + b1) + (b2 + b3) + self_c[idx];
    float og = outgate[idx];
    out[idx] = og;
    out[ND + idx] = og * tanhf(C);
    out[2 * ND + idx] = C;
}

extern "C" void kernel_launch(void* const* d_in, const int* in_sizes, int n_in,
                              void* d_out, int out_size, void* d_ws, size_t ws_size,
                              hipStream_t stream) {
    const float* corr    = (const float*)d_in[0];
    const int*   nei     = (const int*)d_in[1];
    const float* outg    = (const float*)d_in[3];
    const float* self_h  = (const float*)d_in[4];
    const float* self_c  = (const float*)d_in[5];
    const float* rel_w1  = (const float*)d_in[6];
    const float* rel_b1  = (const float*)d_in[7];
    const float* rel_w2  = (const float*)d_in[8];
    const float* rel_b2  = (const float*)d_in[9];
    const float* ngate_w = (const float*)d_in[10];
    const float* ngate_b = (const float*)d_in[11];
    const float* war_w   = (const float*)d_in[12];
    const float* war_b   = (const float*)d_in[13];
    const float* wnei_w1 = (const float*)d_in[14];
    const float* wnei_b1 = (const float*)d_in[15];
    const float* wnei_w2 = (const float*)d_in[16];
    const float* wnei_b2 = (const float*)d_in[17];

    float* ws      = (float*)d_ws;
    float* tt      = ws;                       // NN
    float* pos     = ws + NN;                  // NN
    float* A       = ws + 2 * NN;              // ND
    float* Bm      = ws + 2 * NN + ND;         // ND
    float* u       = ws + 2 * NN + 2 * ND;     // N
    float* v       = u + N;                    // N
    float* partial = v + N;                    // NCHUNK*ND
    float* tail    = partial + NCHUNK * ND;
    _Float16* rc16 = (_Float16*)tail;          // NN*R fp16 = NN*R/2 floats
    _Float16* wf   = rc16 + (size_t)NN * R;    // 2*16*64*8 fp16
    size_t base_floats = (size_t)(2 * NN + 2 * ND + 2 * N + NCHUNK * ND);
    size_t need = (base_floats + ((size_t)NN * R + 2 * 16 * 64 * 8) / 2 + 16) * sizeof(float);
    bool use_rc = ws_size >= need;
    float* out = (float*)d_out;

    precompute_kernel<<<N, 256, 0, stream>>>(self_h, ngate_w, war_w, A, Bm, u, v);
    if (use_rc) {
        wfrag_kernel<<<32, 64, 0, stream>>>(ngate_w, wf);
        tt_mfma_kernel<<<NN / 256, 256, 0, stream>>>(corr, rel_w1, rel_b1, rel_w2, rel_b2,
                                                     war_w, war_b, u, v, tt, rc16);
    } else {
        tt_valu_kernel<<<NN / TPB, 256, 0, stream>>>(corr, rel_w1, rel_b1, rel_w2, rel_b2,
                                                     war_w, war_b, u, v, tt);
    }
    softmax_kernel<<<N, 256, 0, stream>>>(tt, nei, pos);
    dim3 ggrid(N, NCHUNK);
    if (use_rc) {
        gate_mfma_kernel<<<ggrid, 256, 0, stream>>>(rc16, wf, ngate_b, A, Bm, pos, self_h,
                                                    partial);
    } else {
        gate_norc_kernel<<<ggrid, 256, 0, stream>>>(corr, rel_w1, rel_b1, rel_w2, rel_b2,
                                                    ngate_w, ngate_b, A, Bm, pos, self_h,
                                                    partial);
    }
    final_kernel<<<N, 256, 0, stream>>>(partial, wnei_w1, wnei_b1, wnei_w2, wnei_b2,
                                        self_c, outg, out);
}

// Round 6
// 78.780 us; speedup vs baseline: 9.1229x; 1.1447x over previous
//
#include <hip/hip_runtime.h>
#include <hip/hip_bf16.h>
#include <math.h>

#define N 384
#define D 256
#define R 64
#define RELH 128
#define NN (N*N)
#define ND (N*D)
#define JCHUNK 64
#define NCHUNK (N / JCHUNK)   // 6
#define TPB 16                // legacy tt pairs per block (fallback)
#define LOG2E 1.44269504088896f

typedef _Float16 f16x8 __attribute__((ext_vector_type(8)));
typedef float f32x4 __attribute__((ext_vector_type(4)));

__device__ __forceinline__ float fast_sigmoid(float x) {
    // rcp(1 + 2^(-x*log2e)); v_exp_f32 + v_rcp_f32, ~1 ulp each
    float e = __builtin_amdgcn_exp2f(-LOG2E * x);
    return __builtin_amdgcn_rcpf(1.f + e);
}
__device__ __forceinline__ float fast_exp(float x) {
    return __builtin_amdgcn_exp2f(LOG2E * x);
}
__device__ __forceinline__ float fast_tanh(float x) {
    // 1 - 2/(1+2^(2x*log2e)); saturates to +-1 for large |x|
    float e = __builtin_amdgcn_exp2f(2.f * LOG2E * x);
    return 1.f - 2.f * __builtin_amdgcn_rcpf(1.f + e);
}

// ---------------------------------------------------------------------------
// Precompute A[i,d] = h_i . ngate_w[64+t, d], B[j,d] = h_j . ngate_w[320+t, d]
// u[i] = h_i . war_w[64:320], v[j] = h_j . war_w[320:576]
// ---------------------------------------------------------------------------
__global__ void precompute_kernel(const float* __restrict__ self_h,
                                  const float* __restrict__ ngate_w,
                                  const float* __restrict__ war_w,
                                  float* __restrict__ A, float* __restrict__ B,
                                  float* __restrict__ u, float* __restrict__ v) {
    __shared__ float hrow[D];
    __shared__ float red[8];
    int i = blockIdx.x, d = threadIdx.x;
    hrow[d] = self_h[i * D + d];
    __syncthreads();
    float a0 = 0.f, a1 = 0.f, b0 = 0.f, b1 = 0.f;
    const float4* hv = (const float4*)hrow;
    #pragma unroll 4
    for (int t4 = 0; t4 < D / 4; ++t4) {
        float4 h = hv[t4];
        int t = t4 * 4;
        a0 = fmaf(h.x, ngate_w[(R + t) * D + d], a0);
        a1 = fmaf(h.y, ngate_w[(R + t + 1) * D + d], a1);
        a0 = fmaf(h.z, ngate_w[(R + t + 2) * D + d], a0);
        a1 = fmaf(h.w, ngate_w[(R + t + 3) * D + d], a1);
        b0 = fmaf(h.x, ngate_w[(R + D + t) * D + d], b0);
        b1 = fmaf(h.y, ngate_w[(R + D + t + 1) * D + d], b1);
        b0 = fmaf(h.z, ngate_w[(R + D + t + 2) * D + d], b0);
        b1 = fmaf(h.w, ngate_w[(R + D + t + 3) * D + d], b1);
    }
    A[i * D + d] = a0 + a1;
    B[i * D + d] = b0 + b1;
    float pu = hrow[d] * war_w[R + d];
    float pv = hrow[d] * war_w[R + D + d];
    for (int off = 32; off; off >>= 1) {
        pu += __shfl_down(pu, off);
        pv += __shfl_down(pv, off);
    }
    int lane = d & 63, w = d >> 6;
    if (lane == 0) { red[w] = pu; red[4 + w] = pv; }
    __syncthreads();
    if (d == 0) {
        u[i] = red[0] + red[1] + red[2] + red[3];
        v[i] = red[4] + red[5] + red[6] + red[7];
    }
}

// ---------------------------------------------------------------------------
// Build fp16 B-fragment buffer for ngate_w[0:64, :], fragment-ordered.
// ---------------------------------------------------------------------------
__global__ void wfrag_kernel(const float* __restrict__ ngate_w,
                             _Float16* __restrict__ wf) {
    int s = blockIdx.x >> 4, t = blockIdx.x & 15;
    int lane = threadIdx.x;
    int lg = lane >> 4, ln = lane & 15;
    #pragma unroll
    for (int i = 0; i < 8; ++i) {
        float w = ngate_w[(s * 32 + lg * 8 + i) * D + t * 16 + ln];
        wf[((size_t)(s * 16 + t) * 64 + lane) * 8 + i] = (_Float16)w;
    }
}

// ---------------------------------------------------------------------------
// MFMA tt: r = relu(relu(corr@W1+b1)@W2+b2) via f16 MFMA (fp32 accum),
// rc stored FP16; tt[p] = r.war_w[0:64] + u[i] + v[j] + war_b.
// ---------------------------------------------------------------------------
__global__ __launch_bounds__(256, 2) void tt_mfma_kernel(
        const float* __restrict__ corr,
        const float* __restrict__ rel_w1, const float* __restrict__ rel_b1,
        const float* __restrict__ rel_w2, const float* __restrict__ rel_b2,
        const float* __restrict__ war_w, const float* __restrict__ war_b,
        const float* __restrict__ u, const float* __restrict__ v,
        float* __restrict__ tt, _Float16* __restrict__ rc) {
    int tid = threadIdx.x;
    int w = tid >> 6, l = tid & 63;
    int lg = l >> 4;          // k-group 0..3
    int ln = l & 15;          // row/col within tile

    f16x8 bfr[4][4];
    #pragma unroll
    for (int s = 0; s < 4; ++s)
        #pragma unroll
        for (int nt = 0; nt < 4; ++nt)
            #pragma unroll
            for (int i = 0; i < 8; ++i)
                bfr[s][nt][i] = (_Float16)rel_w2[(s * 32 + lg * 8 + i) * R + nt * 16 + ln];
    float w10[4][8], w11[4][8], b1v[4][8];
    #pragma unroll
    for (int s = 0; s < 4; ++s)
        #pragma unroll
        for (int i = 0; i < 8; ++i) {
            int hk = s * 32 + lg * 8 + i;
            w10[s][i] = rel_w1[hk];
            w11[s][i] = rel_w1[RELH + hk];
            b1v[s][i] = rel_b1[hk];
        }
    float b2r[4], warw[4];
    #pragma unroll
    for (int nt = 0; nt < 4; ++nt) {
        b2r[nt]  = rel_b2[nt * 16 + ln];
        warw[nt] = war_w[nt * 16 + ln];
    }
    float wb = war_b[0];

    #pragma unroll
    for (int t = 0; t < 4; ++t) {
        int P0 = blockIdx.x * 256 + w * 64 + t * 16;
        float2 x = ((const float2*)corr)[P0 + ln];
        f16x8 af[4];
        #pragma unroll
        for (int s = 0; s < 4; ++s)
            #pragma unroll
            for (int i = 0; i < 8; ++i) {
                float h = fmaxf(0.f, fmaf(x.y, w11[s][i], fmaf(x.x, w10[s][i], b1v[s][i])));
                af[s][i] = (_Float16)h;
            }
        f32x4 c[4];
        #pragma unroll
        for (int nt = 0; nt < 4; ++nt) c[nt] = (f32x4){0.f, 0.f, 0.f, 0.f};
        #pragma unroll
        for (int nt = 0; nt < 4; ++nt)
            #pragma unroll
            for (int s = 0; s < 4; ++s)
                c[nt] = __builtin_amdgcn_mfma_f32_16x16x32_f16(af[s], bfr[s][nt], c[nt], 0, 0, 0);
        float tpart[4] = {0.f, 0.f, 0.f, 0.f};
        #pragma unroll
        for (int nt = 0; nt < 4; ++nt)
            #pragma unroll
            for (int reg = 0; reg < 4; ++reg) {
                float rv = fmaxf(0.f, c[nt][reg] + b2r[nt]);
                int m = lg * 4 + reg;
                rc[(size_t)(P0 + m) * R + nt * 16 + ln] = (_Float16)rv;
                tpart[reg] = fmaf(rv, warw[nt], tpart[reg]);
            }
        #pragma unroll
        for (int reg = 0; reg < 4; ++reg) {
            float tsum = tpart[reg];
            #pragma unroll
            for (int off = 8; off; off >>= 1) tsum += __shfl_xor(tsum, off, 16);
            tpart[reg] = tsum;
        }
        if (ln == 0) {
            #pragma unroll
            for (int reg = 0; reg < 4; ++reg) {
                int p = P0 + lg * 4 + reg;
                int i = p / N, j = p - i * N;
                tt[p] = tpart[reg] + u[i] + v[j] + wb;
            }
        }
    }
}

// ---------------------------------------------------------------------------
// Fallback VALU tt (only if workspace too small for rcache).
// ---------------------------------------------------------------------------
__global__ __launch_bounds__(256) void tt_valu_kernel(
        const float* __restrict__ corr,
        const float* __restrict__ rel_w1, const float* __restrict__ rel_b1,
        const float* __restrict__ rel_w2, const float* __restrict__ rel_b2,
        const float* __restrict__ war_w, const float* __restrict__ war_b,
        const float* __restrict__ u, const float* __restrict__ v,
        float* __restrict__ tt) {
    __shared__ __align__(16) float h1s[4][RELH];
    int tid = threadIdx.x, w = tid >> 6, l = tid & 63;
    float w1a0 = rel_w1[l],      w1a1 = rel_w1[RELH + l];
    float w1b0 = rel_w1[64 + l], w1b1 = rel_w1[RELH + 64 + l];
    float b1a = rel_b1[l], b1b = rel_b1[64 + l];
    float b2v = rel_b2[l], warw = war_w[l], wb = war_b[0];
    int pbase = blockIdx.x * TPB;
    #pragma unroll
    for (int it = 0; it < TPB / 4; ++it) {
        int p = pbase + it * 4 + w;
        int i = p / N, j = p - i * N;
        float2 x = *(const float2*)(corr + p * 2);
        h1s[w][l]      = fmaxf(0.f, fmaf(x.y, w1a1, fmaf(x.x, w1a0, b1a)));
        h1s[w][l + 64] = fmaxf(0.f, fmaf(x.y, w1b1, fmaf(x.x, w1b0, b1b)));
        float c0 = b2v, c1 = 0.f, c2 = 0.f, c3 = 0.f;
        const float4* hv = (const float4*)h1s[w];
        #pragma unroll
        for (int k4 = 0; k4 < RELH / 4; ++k4) {
            float4 h = hv[k4];
            c0 = fmaf(h.x, rel_w2[(k4 * 4 + 0) * R + l], c0);
            c1 = fmaf(h.y, rel_w2[(k4 * 4 + 1) * R + l], c1);
            c2 = fmaf(h.z, rel_w2[(k4 * 4 + 2) * R + l], c2);
            c3 = fmaf(h.w, rel_w2[(k4 * 4 + 3) * R + l], c3);
        }
        float rm = fmaxf(0.f, (c0 + c1) + (c2 + c3));
        float part = rm * warw;
        for (int off = 32; off; off >>= 1) part += __shfl_down(part, off);
        if (l == 0) tt[p] = part + u[i] + v[j] + wb;
    }
}

// ---------------------------------------------------------------------------
// Row softmax over valid entries (mask && tt != 0), zeros elsewhere.
// ---------------------------------------------------------------------------
__global__ void softmax_kernel(const float* __restrict__ tt,
                               const int* __restrict__ nei,
                               float* __restrict__ pos) {
    __shared__ float red[4];
    __shared__ float sM, sS;
    int i = blockIdx.x, tid = threadIdx.x;
    float tv[2]; bool valid[2];
    float m = -INFINITY;
    for (int s = 0; s < 2; ++s) {
        int j = tid + s * 256;
        valid[s] = false; tv[s] = 0.f;
        if (j < N) {
            float t = tt[i * N + j];
            bool va = (nei[i * N + j] > 0) && (t != 0.f);
            tv[s] = t; valid[s] = va;
            if (va) m = fmaxf(m, t);
        }
    }
    for (int off = 32; off; off >>= 1) m = fmaxf(m, __shfl_down(m, off));
    if ((tid & 63) == 0) red[tid >> 6] = m;
    __syncthreads();
    if (tid == 0) sM = fmaxf(fmaxf(red[0], red[1]), fmaxf(red[2], red[3]));
    __syncthreads();
    float M = sM;
    float e[2] = {0.f, 0.f};
    float sum = 0.f;
    if (M != -INFINITY) {
        for (int s = 0; s < 2; ++s)
            if (valid[s]) { e[s] = fast_exp(tv[s] - M); sum += e[s]; }
    }
    for (int off = 32; off; off >>= 1) sum += __shfl_down(sum, off);
    if ((tid & 63) == 0) red[tid >> 6] = sum;
    __syncthreads();
    if (tid == 0) sS = red[0] + red[1] + red[2] + red[3];
    __syncthreads();
    float rden = (sS > 0.f) ? __builtin_amdgcn_rcpf(sS) : 0.f;
    for (int s = 0; s < 2; ++s) {
        int j = tid + s * 256;
        if (j < N) pos[i * N + j] = valid[s] ? e[s] * rden : 0.f;
    }
}

// ---------------------------------------------------------------------------
// MFMA gate: per (i, jchunk) block, logits L[64j x 256d] = r @ ngate_w[0:64,:]
// via f16 MFMA with Bm folded into the C-input; then
// acc[d] += pos[j]*h[j,d]*fast_sigmoid(L + base[d]).
// ---------------------------------------------------------------------------
__global__ __launch_bounds__(256, 2) void gate_mfma_kernel(
        const _Float16* __restrict__ rc16, const _Float16* __restrict__ wf,
        const float* __restrict__ ngate_b, const float* __restrict__ A,
        const float* __restrict__ Bm, const float* __restrict__ pos,
        const float* __restrict__ self_h, float* __restrict__ partial) {
    int i = blockIdx.x;
    int jbase = blockIdx.y * JCHUNK;
    int tid = threadIdx.x, w = tid >> 6, l = tid & 63;
    int lg = l >> 4, ln = l & 15;

    // B fragments: dtiles w*4 .. w*4+3
    f16x8 bf[2][4];
    #pragma unroll
    for (int s = 0; s < 2; ++s)
        #pragma unroll
        for (int t = 0; t < 4; ++t)
            bf[s][t] = *(const f16x8*)&wf[((size_t)(s * 16 + w * 4 + t) * 64 + l) * 8];

    // A fragments: af[jt][s], row = jbase + jt*16 + ln, k = s*32 + lg*8 + i
    f16x8 af[4][2];
    #pragma unroll
    for (int jt = 0; jt < 4; ++jt)
        #pragma unroll
        for (int s = 0; s < 2; ++s)
            af[jt][s] = *(const f16x8*)&rc16[(size_t)(i * N + jbase + jt * 16 + ln) * R + s * 32 + lg * 8];

    // pos values this thread's epilogue touches: jj = jbase + jt*16 + lg*4 + reg
    float pj[4][4];
    #pragma unroll
    for (int jt = 0; jt < 4; ++jt)
        #pragma unroll
        for (int reg = 0; reg < 4; ++reg)
            pj[jt][reg] = pos[i * N + jbase + jt * 16 + lg * 4 + reg];

    float based[4];
    #pragma unroll
    for (int t = 0; t < 4; ++t) {
        int d = w * 64 + t * 16 + ln;
        based[t] = ngate_b[d] + A[i * D + d];
    }

    float acc[4] = {0.f, 0.f, 0.f, 0.f};
    #pragma unroll
    for (int jt = 0; jt < 4; ++jt) {
        f32x4 c[4];
        // C-input = Bm (free add): c[t][reg] at row jj=jbase+jt*16+lg*4+reg, col d
        #pragma unroll
        for (int t = 0; t < 4; ++t) {
            int d = w * 64 + t * 16 + ln;
            #pragma unroll
            for (int reg = 0; reg < 4; ++reg)
                c[t][reg] = Bm[(size_t)(jbase + jt * 16 + lg * 4 + reg) * D + d];
        }
        #pragma unroll
        for (int t = 0; t < 4; ++t)
            #pragma unroll
            for (int s = 0; s < 2; ++s)
                c[t] = __builtin_amdgcn_mfma_f32_16x16x32_f16(af[jt][s], bf[s][t], c[t], 0, 0, 0);
        #pragma unroll
        for (int reg = 0; reg < 4; ++reg) {
            int jj = jbase + jt * 16 + lg * 4 + reg;
            float p = pj[jt][reg];
            #pragma unroll
            for (int t = 0; t < 4; ++t) {
                int d = w * 64 + t * 16 + ln;
                float h  = self_h[jj * D + d];
                float g = fast_sigmoid(c[t][reg] + based[t]);
                acc[t] = fmaf(p * h, g, acc[t]);
            }
        }
    }
    // reduce over the 4 lane-groups (different j subsets, same d)
    #pragma unroll
    for (int t = 0; t < 4; ++t) {
        float a = acc[t];
        a += __shfl_xor(a, 16);
        a += __shfl_xor(a, 32);
        acc[t] = a;
    }
    if (lg == 0) {
        #pragma unroll
        for (int t = 0; t < 4; ++t)
            partial[(size_t)(blockIdx.y * N + i) * D + w * 64 + t * 16 + ln] = acc[t];
    }
}

// ---------------------------------------------------------------------------
// Fallback gate (no rcache): recompute rel MLP per active pair.
// ---------------------------------------------------------------------------
__global__ void gate_norc_kernel(const float* __restrict__ corr,
                            const float* __restrict__ rel_w1, const float* __restrict__ rel_b1,
                            const float* __restrict__ rel_w2, const float* __restrict__ rel_b2,
                            const float* __restrict__ ngate_w, const float* __restrict__ ngate_b,
                            const float* __restrict__ A, const float* __restrict__ Bm,
                            const float* __restrict__ pos, const float* __restrict__ self_h,
                            float* __restrict__ partial) {
    __shared__ __align__(16) float h1[4][RELH];
    __shared__ __align__(16) float rs[4][R];
    __shared__ float wsh[4];
    int i = blockIdx.x, tid = threadIdx.x;
    int jbase = blockIdx.y * JCHUNK;
    int w = tid >> 6, l = tid & 63;
    ((float*)rs)[tid] = 0.f;
    float base = ngate_b[tid] + A[i * D + tid];
    float acc = 0.f;
    for (int j0 = jbase; j0 < jbase + JCHUNK; j0 += 4) {
        int j = j0 + w;
        int p = i * N + j;
        float wt = pos[p];
        if (l == 0) wsh[w] = wt;
        if (wt != 0.f) {
            float x0 = corr[p * 2], x1 = corr[p * 2 + 1];
            h1[w][l]      = fmaxf(0.f, fmaf(x1, rel_w1[RELH + l],      fmaf(x0, rel_w1[l],      rel_b1[l])));
            h1[w][l + 64] = fmaxf(0.f, fmaf(x1, rel_w1[RELH + l + 64], fmaf(x0, rel_w1[l + 64], rel_b1[l + 64])));
        }
        __syncthreads();
        if (wsh[w] != 0.f) {
            float c0 = rel_b2[l], c1 = 0.f, c2 = 0.f, c3 = 0.f;
            const float4* hv = (const float4*)h1[w];
            #pragma unroll 8
            for (int k4 = 0; k4 < RELH / 4; ++k4) {
                float4 h = hv[k4];
                int k = k4 * 4;
                c0 = fmaf(h.x, rel_w2[k * R + l], c0);
                c1 = fmaf(h.y, rel_w2[(k + 1) * R + l], c1);
                c2 = fmaf(h.z, rel_w2[(k + 2) * R + l], c2);
                c3 = fmaf(h.w, rel_w2[(k + 3) * R + l], c3);
            }
            rs[w][l] = fmaxf(0.f, (c0 + c1) + (c2 + c3));
        }
        __syncthreads();
        #pragma unroll
        for (int ww = 0; ww < 4; ++ww) {
            float wtj = wsh[ww];
            if (wtj != 0.f) {
                int jj = j0 + ww;
                const float4* rv = (const float4*)rs[ww];
                float l0 = 0.f, l1 = 0.f, l2 = 0.f, l3 = 0.f;
                #pragma unroll 4
                for (int m4 = 0; m4 < R / 4; ++m4) {
                    float4 r4 = rv[m4];
                    int m = m4 * 4;
                    l0 = fmaf(r4.x, ngate_w[m * D + tid], l0);
                    l1 = fmaf(r4.y, ngate_w[(m + 1) * D + tid], l1);
                    l2 = fmaf(r4.z, ngate_w[(m + 2) * D + tid], l2);
                    l3 = fmaf(r4.w, ngate_w[(m + 3) * D + tid], l3);
                }
                float logit = base + Bm[jj * D + tid] + ((l0 + l1) + (l2 + l3));
                float g = fast_sigmoid(logit);
                acc = fmaf(wtj * self_h[jj * D + tid], g, acc);
            }
        }
        __syncthreads();
    }
    partial[(blockIdx.y * N + i) * D + tid] = acc;
}

// ---------------------------------------------------------------------------
// hsum = sum of partials; hidden = relu(hsum@W1+b1); out2 = hidden@W2+b2;
// C = out2 + self_c; H_out = outgate * tanh(C); outputs = (outgate, H_out, C)
// ---------------------------------------------------------------------------
__global__ void final_kernel(const float* __restrict__ partial,
                             const float* __restrict__ wnei_w1, const float* __restrict__ wnei_b1,
                             const float* __restrict__ wnei_w2, const float* __restrict__ wnei_b2,
                             const float* __restrict__ self_c, const float* __restrict__ outgate,
                             float* __restrict__ out) {
    __shared__ __align__(16) float hs[D];
    __shared__ __align__(16) float hid[D];
    int i = blockIdx.x, d = threadIdx.x;
    float s = 0.f;
    #pragma unroll
    for (int c = 0; c < NCHUNK; ++c) s += partial[(c * N + i) * D + d];
    hs[d] = s;
    __syncthreads();
    float a0 = wnei_b1[d], a1 = 0.f, a2 = 0.f, a3 = 0.f;
    const float4* hv = (const float4*)hs;
    #pragma unroll 4
    for (int t4 = 0; t4 < D / 4; ++t4) {
        float4 h = hv[t4];
        int t = t4 * 4;
        a0 = fmaf(h.x, wnei_w1[t * D + d], a0);
        a1 = fmaf(h.y, wnei_w1[(t + 1) * D + d], a1);
        a2 = fmaf(h.z, wnei_w1[(t + 2) * D + d], a2);
        a3 = fmaf(h.w, wnei_w1[(t + 3) * D + d], a3);
    }
    hid[d] = fmaxf(0.f, (a0 + a1) + (a2 + a3));
    __syncthreads();
    float b0 = wnei_b2[d], b1 = 0.f, b2 = 0.f, b3 = 0.f;
    const float4* gv = (const float4*)hid;
    #pragma unroll 4
    for (int t4 = 0; t4 < D / 4; ++t4) {
        float4 h = gv[t4];
        int t = t4 * 4;
        b0 = fmaf(h.x, wnei_w2[t * D + d], b0);
        b1 = fmaf(h.y, wnei_w2[(t + 1) * D + d], b1);
        b2 = fmaf(h.z, wnei_w2[(t + 2) * D + d], b2);
        b3 = fmaf(h.w, wnei_w2[(t + 3) * D + d], b3);
    }
    int idx = i * D + d;
    float C = (b0 + b1) + (b2 + b3) + self_c[idx];
    float og = outgate[idx];
    out[idx] = og;
    out[ND + idx] = og * fast_tanh(C);
    out[2 * ND + idx] = C;
}

extern "C" void kernel_launch(void* const* d_in, const int* in_sizes, int n_in,
                              void* d_out, int out_size, void* d_ws, size_t ws_size,
                              hipStream_t stream) {
    const float* corr    = (const float*)d_in[0];
    const int*   nei     = (const int*)d_in[1];
    const float* outg    = (const float*)d_in[3];
    const float* self_h  = (const float*)d_in[4];
    const float* self_c  = (const float*)d_in[5];
    const float* rel_w1  = (const float*)d_in[6];
    const float* rel_b1  = (const float*)d_in[7];
    const float* rel_w2  = (const float*)d_in[8];
    const float* rel_b2  = (const float*)d_in[9];
    const float* ngate_w = (const float*)d_in[10];
    const float* ngate_b = (const float*)d_in[11];
    const float* war_w   = (const float*)d_in[12];
    const float* war_b   = (const float*)d_in[13];
    const float* wnei_w1 = (const float*)d_in[14];
    const float* wnei_b1 = (const float*)d_in[15];
    const float* wnei_w2 = (const float*)d_in[16];
    const float* wnei_b2 = (const float*)d_in[17];

    float* ws      = (float*)d_ws;
    float* tt      = ws;                       // NN
    float* pos     = ws + NN;                  // NN
    float* A       = ws + 2 * NN;              // ND
    float* Bm      = ws + 2 * NN + ND;         // ND
    float* u       = ws + 2 * NN + 2 * ND;     // N
    float* v       = u + N;                    // N
    float* partial = v + N;                    // NCHUNK*ND
    float* tail    = partial + NCHUNK * ND;
    _Float16* rc16 = (_Float16*)tail;          // NN*R fp16 = NN*R/2 floats
    _Float16* wf   = rc16 + (size_t)NN * R;    // 2*16*64*8 fp16
    size_t base_floats = (size_t)(2 * NN + 2 * ND + 2 * N + NCHUNK * ND);
    size_t need = (base_floats + ((size_t)NN * R + 2 * 16 * 64 * 8) / 2 + 16) * sizeof(float);
    bool use_rc = ws_size >= need;
    float* out = (float*)d_out;

    precompute_kernel<<<N, 256, 0, stream>>>(self_h, ngate_w, war_w, A, Bm, u, v);
    if (use_rc) {
        wfrag_kernel<<<32, 64, 0, stream>>>(ngate_w, wf);
        tt_mfma_kernel<<<NN / 256, 256, 0, stream>>>(corr, rel_w1, rel_b1, rel_w2, rel_b2,
                                                     war_w, war_b, u, v, tt, rc16);
    } else {
        tt_valu_kernel<<<NN / TPB, 256, 0, stream>>>(corr, rel_w1, rel_b1, rel_w2, rel_b2,
                                                     war_w, war_b, u, v, tt);
    }
    softmax_kernel<<<N, 256, 0, stream>>>(tt, nei, pos);
    dim3 ggrid(N, NCHUNK);
    if (use_rc) {
        gate_mfma_kernel<<<ggrid, 256, 0, stream>>>(rc16, wf, ngate_b, A, Bm, pos, self_h,
                                                    partial);
    } else {
        gate_norc_kernel<<<ggrid, 256, 0, stream>>>(corr, rel_w1, rel_b1, rel_w2, rel_b2,
                                                    ngate_w, ngate_b, A, Bm, pos, self_h,
                                                    partial);
    }
    final_kernel<<<N, 256, 0, stream>>>(partial, wnei_w1, wnei_b1, wnei_w2, wnei_b2,
                                        self_c, outg, out);
}

// Round 7
// 71.228 us; speedup vs baseline: 10.0901x; 1.1060x over previous
//
#include <hip/hip_runtime.h>
#include <hip/hip_bf16.h>
#include <math.h>

#define N 384
#define D 256
#define R 64
#define RELH 128
#define NN (N*N)
#define ND (N*D)
#define JCHUNK 64
#define NCHUNK (N / JCHUNK)   // 6
#define TPB 16                // legacy tt pairs per block (fallback)
#define LOG2E 1.44269504088896f

typedef _Float16 f16x8 __attribute__((ext_vector_type(8)));
typedef float f32x4 __attribute__((ext_vector_type(4)));

__device__ __forceinline__ float fast_sigmoid(float x) {
    float e = __builtin_amdgcn_exp2f(-LOG2E * x);
    return __builtin_amdgcn_rcpf(1.f + e);
}
__device__ __forceinline__ float fast_exp(float x) {
    return __builtin_amdgcn_exp2f(LOG2E * x);
}
__device__ __forceinline__ float fast_tanh(float x) {
    float e = __builtin_amdgcn_exp2f(2.f * LOG2E * x);
    return 1.f - 2.f * __builtin_amdgcn_rcpf(1.f + e);
}

// ---------------------------------------------------------------------------
// prep_kernel: role-switched on blockIdx.x (62 blocks x 256 threads)
//  b in [0,6):   u[row]/v[row] wave reductions, 64 rows per block
//  b in [6,54):  [A | Bm] = self_h @ ngate_w[64:576] via fp16 MFMA GEMM
//                (192 waves; wave = 16 rows x 64 cols of the 384x512 output)
//  b in [54,62): wfrag: fp16 fragment-ordered copy of ngate_w[0:64,:]
// ---------------------------------------------------------------------------
__global__ __launch_bounds__(256) void prep_kernel(
        const float* __restrict__ self_h, const float* __restrict__ ngate_w,
        const float* __restrict__ war_w,
        float* __restrict__ A, float* __restrict__ Bm,
        float* __restrict__ u, float* __restrict__ v,
        _Float16* __restrict__ wf) {
    int b = blockIdx.x, tid = threadIdx.x;
    int wv = tid >> 6, l = tid & 63;
    int lg = l >> 4, ln = l & 15;

    if (b < 6) {
        // u/v: 4 waves x 16 rows each
        int r0 = b * 64 + wv * 16;
        for (int rr = 0; rr < 16; ++rr) {
            int row = r0 + rr;
            float su = 0.f, sv = 0.f;
            #pragma unroll
            for (int k = 0; k < 4; ++k) {
                int d = k * 64 + l;
                float h = self_h[row * D + d];
                su = fmaf(h, war_w[R + d], su);
                sv = fmaf(h, war_w[R + D + d], sv);
            }
            #pragma unroll
            for (int off = 32; off; off >>= 1) {
                su += __shfl_down(su, off);
                sv += __shfl_down(sv, off);
            }
            if (l == 0) { u[row] = su; v[row] = sv; }
        }
    } else if (b < 54) {
        int W = (b - 6) * 4 + wv;        // 0..191
        int m0 = (W >> 3) * 16;          // row block
        int cb = (W & 7) * 64;           // col base in [0,512)
        const float* wsrc = ngate_w + (size_t)(cb >= 256 ? 320 : 64) * D + (cb & 255);
        f32x4 acc[4];
        #pragma unroll
        for (int nt = 0; nt < 4; ++nt) acc[nt] = (f32x4){0.f, 0.f, 0.f, 0.f};
        #pragma unroll
        for (int s = 0; s < 8; ++s) {
            const float4* hp = (const float4*)&self_h[(size_t)(m0 + ln) * D + s * 32 + lg * 8];
            float4 h0 = hp[0], h1 = hp[1];
            f16x8 af;
            af[0] = (_Float16)h0.x; af[1] = (_Float16)h0.y;
            af[2] = (_Float16)h0.z; af[3] = (_Float16)h0.w;
            af[4] = (_Float16)h1.x; af[5] = (_Float16)h1.y;
            af[6] = (_Float16)h1.z; af[7] = (_Float16)h1.w;
            #pragma unroll
            for (int nt = 0; nt < 4; ++nt) {
                f16x8 bf;
                #pragma unroll
                for (int ii = 0; ii < 8; ++ii)
                    bf[ii] = (_Float16)wsrc[(size_t)(s * 32 + lg * 8 + ii) * D + nt * 16 + ln];
                acc[nt] = __builtin_amdgcn_mfma_f32_16x16x32_f16(af, bf, acc[nt], 0, 0, 0);
            }
        }
        #pragma unroll
        for (int nt = 0; nt < 4; ++nt)
            #pragma unroll
            for (int reg = 0; reg < 4; ++reg) {
                int row = m0 + lg * 4 + reg;
                int col = cb + nt * 16 + ln;
                if (col < 256) A[row * D + col] = acc[nt][reg];
                else           Bm[row * D + (col - 256)] = acc[nt][reg];
            }
    } else {
        int blkEq = (b - 54) * 4 + wv;   // 0..31
        int s = blkEq >> 4, t = blkEq & 15;
        #pragma unroll
        for (int ii = 0; ii < 8; ++ii) {
            float w = ngate_w[(s * 32 + lg * 8 + ii) * D + t * 16 + ln];
            wf[((size_t)(s * 16 + t) * 64 + l) * 8 + ii] = (_Float16)w;
        }
    }
}

// ---------------------------------------------------------------------------
// ttsm_kernel: one block per row i (384 threads = 6 waves).
// Wave wv computes r for pairs j in [wv*64, wv*64+64) via f16 MFMA, stores
// rc16, and writes the war-logit (r.war_w + v[j]; u[i]/war_b are row-constant
// -> softmax-invariant -> dropped) into LDS ttrow. Then block softmax -> pos.
// ---------------------------------------------------------------------------
__global__ __launch_bounds__(384) void ttsm_kernel(
        const float* __restrict__ corr,
        const float* __restrict__ rel_w1, const float* __restrict__ rel_b1,
        const float* __restrict__ rel_w2, const float* __restrict__ rel_b2,
        const float* __restrict__ war_w, const float* __restrict__ v,
        const int* __restrict__ nei,
        float* __restrict__ pos, _Float16* __restrict__ rc) {
    __shared__ float ttrow[N];
    __shared__ float red[6];
    __shared__ float sM, sS;
    int i = blockIdx.x, tid = threadIdx.x;
    int wv = tid >> 6, l = tid & 63;
    int lg = l >> 4, ln = l & 15;

    f16x8 bfr[4][4];
    #pragma unroll
    for (int s = 0; s < 4; ++s)
        #pragma unroll
        for (int nt = 0; nt < 4; ++nt)
            #pragma unroll
            for (int ii = 0; ii < 8; ++ii)
                bfr[s][nt][ii] = (_Float16)rel_w2[(s * 32 + lg * 8 + ii) * R + nt * 16 + ln];
    float w10[4][8], w11[4][8], b1v[4][8];
    #pragma unroll
    for (int s = 0; s < 4; ++s)
        #pragma unroll
        for (int ii = 0; ii < 8; ++ii) {
            int hk = s * 32 + lg * 8 + ii;
            w10[s][ii] = rel_w1[hk];
            w11[s][ii] = rel_w1[RELH + hk];
            b1v[s][ii] = rel_b1[hk];
        }
    float b2r[4], warw[4];
    #pragma unroll
    for (int nt = 0; nt < 4; ++nt) {
        b2r[nt]  = rel_b2[nt * 16 + ln];
        warw[nt] = war_w[nt * 16 + ln];
    }

    #pragma unroll
    for (int t = 0; t < 4; ++t) {
        int j0 = wv * 64 + t * 16;
        int P0 = i * N + j0;
        float2 x = ((const float2*)corr)[P0 + ln];
        f16x8 af[4];
        #pragma unroll
        for (int s = 0; s < 4; ++s)
            #pragma unroll
            for (int ii = 0; ii < 8; ++ii) {
                float h = fmaxf(0.f, fmaf(x.y, w11[s][ii], fmaf(x.x, w10[s][ii], b1v[s][ii])));
                af[s][ii] = (_Float16)h;
            }
        f32x4 c[4];
        #pragma unroll
        for (int nt = 0; nt < 4; ++nt) c[nt] = (f32x4){0.f, 0.f, 0.f, 0.f};
        #pragma unroll
        for (int nt = 0; nt < 4; ++nt)
            #pragma unroll
            for (int s = 0; s < 4; ++s)
                c[nt] = __builtin_amdgcn_mfma_f32_16x16x32_f16(af[s], bfr[s][nt], c[nt], 0, 0, 0);
        float tpart[4] = {0.f, 0.f, 0.f, 0.f};
        #pragma unroll
        for (int nt = 0; nt < 4; ++nt)
            #pragma unroll
            for (int reg = 0; reg < 4; ++reg) {
                float rv = fmaxf(0.f, c[nt][reg] + b2r[nt]);
                int m = lg * 4 + reg;
                rc[(size_t)(P0 + m) * R + nt * 16 + ln] = (_Float16)rv;
                tpart[reg] = fmaf(rv, warw[nt], tpart[reg]);
            }
        #pragma unroll
        for (int reg = 0; reg < 4; ++reg) {
            float tsum = tpart[reg];
            #pragma unroll
            for (int off = 8; off; off >>= 1) tsum += __shfl_xor(tsum, off, 16);
            tpart[reg] = tsum;
        }
        if (ln == 0) {
            #pragma unroll
            for (int reg = 0; reg < 4; ++reg) {
                int j = j0 + lg * 4 + reg;
                ttrow[j] = tpart[reg] + v[j];
            }
        }
    }
    __syncthreads();

    // ---- softmax over ttrow[0..383] ----
    float tv = ttrow[tid];
    bool va = (nei[i * N + tid] > 0) && (tv != 0.f);
    float m = va ? tv : -INFINITY;
    #pragma unroll
    for (int off = 32; off; off >>= 1) m = fmaxf(m, __shfl_down(m, off));
    if (l == 0) red[wv] = m;
    __syncthreads();
    if (tid == 0) {
        float mm = red[0];
        #pragma unroll
        for (int k = 1; k < 6; ++k) mm = fmaxf(mm, red[k]);
        sM = mm;
    }
    __syncthreads();
    float M = sM;
    float e = 0.f;
    if (va && M != -INFINITY) e = fast_exp(tv - M);
    float sum = e;
    #pragma unroll
    for (int off = 32; off; off >>= 1) sum += __shfl_down(sum, off);
    if (l == 0) red[wv] = sum;
    __syncthreads();
    if (tid == 0) {
        float ss = red[0];
        #pragma unroll
        for (int k = 1; k < 6; ++k) ss += red[k];
        sS = ss;
    }
    __syncthreads();
    float rden = (sS > 0.f) ? __builtin_amdgcn_rcpf(sS) : 0.f;
    pos[i * N + tid] = va ? e * rden : 0.f;
}

// ---------------------------------------------------------------------------
// Fallback VALU tt (only if workspace too small for rcache).
// ---------------------------------------------------------------------------
__global__ __launch_bounds__(256) void tt_valu_kernel(
        const float* __restrict__ corr,
        const float* __restrict__ rel_w1, const float* __restrict__ rel_b1,
        const float* __restrict__ rel_w2, const float* __restrict__ rel_b2,
        const float* __restrict__ war_w, const float* __restrict__ war_b,
        const float* __restrict__ u, const float* __restrict__ v,
        float* __restrict__ tt) {
    __shared__ __align__(16) float h1s[4][RELH];
    int tid = threadIdx.x, w = tid >> 6, l = tid & 63;
    float w1a0 = rel_w1[l],      w1a1 = rel_w1[RELH + l];
    float w1b0 = rel_w1[64 + l], w1b1 = rel_w1[RELH + 64 + l];
    float b1a = rel_b1[l], b1b = rel_b1[64 + l];
    float b2v = rel_b2[l], warw = war_w[l], wb = war_b[0];
    int pbase = blockIdx.x * TPB;
    #pragma unroll
    for (int it = 0; it < TPB / 4; ++it) {
        int p = pbase + it * 4 + w;
        int i = p / N, j = p - i * N;
        float2 x = *(const float2*)(corr + p * 2);
        h1s[w][l]      = fmaxf(0.f, fmaf(x.y, w1a1, fmaf(x.x, w1a0, b1a)));
        h1s[w][l + 64] = fmaxf(0.f, fmaf(x.y, w1b1, fmaf(x.x, w1b0, b1b)));
        float c0 = b2v, c1 = 0.f, c2 = 0.f, c3 = 0.f;
        const float4* hv = (const float4*)h1s[w];
        #pragma unroll
        for (int k4 = 0; k4 < RELH / 4; ++k4) {
            float4 h = hv[k4];
            c0 = fmaf(h.x, rel_w2[(k4 * 4 + 0) * R + l], c0);
            c1 = fmaf(h.y, rel_w2[(k4 * 4 + 1) * R + l], c1);
            c2 = fmaf(h.z, rel_w2[(k4 * 4 + 2) * R + l], c2);
            c3 = fmaf(h.w, rel_w2[(k4 * 4 + 3) * R + l], c3);
        }
        float rm = fmaxf(0.f, (c0 + c1) + (c2 + c3));
        float part = rm * warw;
        for (int off = 32; off; off >>= 1) part += __shfl_down(part, off);
        if (l == 0) tt[p] = part + u[i] + v[j] + wb;
    }
}

// ---------------------------------------------------------------------------
// Fallback row softmax (256 threads), used only in the no-rcache path.
// ---------------------------------------------------------------------------
__global__ void softmax_kernel(const float* __restrict__ tt,
                               const int* __restrict__ nei,
                               float* __restrict__ pos) {
    __shared__ float red[4];
    __shared__ float sM, sS;
    int i = blockIdx.x, tid = threadIdx.x;
    float tv[2]; bool valid[2];
    float m = -INFINITY;
    for (int s = 0; s < 2; ++s) {
        int j = tid + s * 256;
        valid[s] = false; tv[s] = 0.f;
        if (j < N) {
            float t = tt[i * N + j];
            bool va = (nei[i * N + j] > 0) && (t != 0.f);
            tv[s] = t; valid[s] = va;
            if (va) m = fmaxf(m, t);
        }
    }
    for (int off = 32; off; off >>= 1) m = fmaxf(m, __shfl_down(m, off));
    if ((tid & 63) == 0) red[tid >> 6] = m;
    __syncthreads();
    if (tid == 0) sM = fmaxf(fmaxf(red[0], red[1]), fmaxf(red[2], red[3]));
    __syncthreads();
    float M = sM;
    float e[2] = {0.f, 0.f};
    float sum = 0.f;
    if (M != -INFINITY) {
        for (int s = 0; s < 2; ++s)
            if (valid[s]) { e[s] = fast_exp(tv[s] - M); sum += e[s]; }
    }
    for (int off = 32; off; off >>= 1) sum += __shfl_down(sum, off);
    if ((tid & 63) == 0) red[tid >> 6] = sum;
    __syncthreads();
    if (tid == 0) sS = red[0] + red[1] + red[2] + red[3];
    __syncthreads();
    float rden = (sS > 0.f) ? __builtin_amdgcn_rcpf(sS) : 0.f;
    for (int s = 0; s < 2; ++s) {
        int j = tid + s * 256;
        if (j < N) pos[i * N + j] = valid[s] ? e[s] * rden : 0.f;
    }
}

// ---------------------------------------------------------------------------
// MFMA gate: per (i, jchunk) block, logits L[64j x 256d] = r @ ngate_w[0:64,:]
// via f16 MFMA with Bm folded into the C-input; then
// acc[d] += pos[j]*h[j,d]*fast_sigmoid(L + base[d]).
// ---------------------------------------------------------------------------
__global__ __launch_bounds__(256, 2) void gate_mfma_kernel(
        const _Float16* __restrict__ rc16, const _Float16* __restrict__ wf,
        const float* __restrict__ ngate_b, const float* __restrict__ A,
        const float* __restrict__ Bm, const float* __restrict__ pos,
        const float* __restrict__ self_h, float* __restrict__ partial) {
    int i = blockIdx.x;
    int jbase = blockIdx.y * JCHUNK;
    int tid = threadIdx.x, w = tid >> 6, l = tid & 63;
    int lg = l >> 4, ln = l & 15;

    f16x8 bf[2][4];
    #pragma unroll
    for (int s = 0; s < 2; ++s)
        #pragma unroll
        for (int t = 0; t < 4; ++t)
            bf[s][t] = *(const f16x8*)&wf[((size_t)(s * 16 + w * 4 + t) * 64 + l) * 8];

    f16x8 af[4][2];
    #pragma unroll
    for (int jt = 0; jt < 4; ++jt)
        #pragma unroll
        for (int s = 0; s < 2; ++s)
            af[jt][s] = *(const f16x8*)&rc16[(size_t)(i * N + jbase + jt * 16 + ln) * R + s * 32 + lg * 8];

    float pj[4][4];
    #pragma unroll
    for (int jt = 0; jt < 4; ++jt)
        #pragma unroll
        for (int reg = 0; reg < 4; ++reg)
            pj[jt][reg] = pos[i * N + jbase + jt * 16 + lg * 4 + reg];

    float based[4];
    #pragma unroll
    for (int t = 0; t < 4; ++t) {
        int d = w * 64 + t * 16 + ln;
        based[t] = ngate_b[d] + A[i * D + d];
    }

    float acc[4] = {0.f, 0.f, 0.f, 0.f};
    #pragma unroll
    for (int jt = 0; jt < 4; ++jt) {
        f32x4 c[4];
        #pragma unroll
        for (int t = 0; t < 4; ++t) {
            int d = w * 64 + t * 16 + ln;
            #pragma unroll
            for (int reg = 0; reg < 4; ++reg)
                c[t][reg] = Bm[(size_t)(jbase + jt * 16 + lg * 4 + reg) * D + d];
        }
        #pragma unroll
        for (int t = 0; t < 4; ++t)
            #pragma unroll
            for (int s = 0; s < 2; ++s)
                c[t] = __builtin_amdgcn_mfma_f32_16x16x32_f16(af[jt][s], bf[s][t], c[t], 0, 0, 0);
        #pragma unroll
        for (int reg = 0; reg < 4; ++reg) {
            int jj = jbase + jt * 16 + lg * 4 + reg;
            float p = pj[jt][reg];
            #pragma unroll
            for (int t = 0; t < 4; ++t) {
                int d = w * 64 + t * 16 + ln;
                float h  = self_h[jj * D + d];
                float g = fast_sigmoid(c[t][reg] + based[t]);
                acc[t] = fmaf(p * h, g, acc[t]);
            }
        }
    }
    #pragma unroll
    for (int t = 0; t < 4; ++t) {
        float a = acc[t];
        a += __shfl_xor(a, 16);
        a += __shfl_xor(a, 32);
        acc[t] = a;
    }
    if (lg == 0) {
        #pragma unroll
        for (int t = 0; t < 4; ++t)
            partial[(size_t)(blockIdx.y * N + i) * D + w * 64 + t * 16 + ln] = acc[t];
    }
}

// ---------------------------------------------------------------------------
// Fallback gate (no rcache): recompute rel MLP per active pair.
// ---------------------------------------------------------------------------
__global__ void gate_norc_kernel(const float* __restrict__ corr,
                            const float* __restrict__ rel_w1, const float* __restrict__ rel_b1,
                            const float* __restrict__ rel_w2, const float* __restrict__ rel_b2,
                            const float* __restrict__ ngate_w, const float* __restrict__ ngate_b,
                            const float* __restrict__ A, const float* __restrict__ Bm,
                            const float* __restrict__ pos, const float* __restrict__ self_h,
                            float* __restrict__ partial) {
    __shared__ __align__(16) float h1[4][RELH];
    __shared__ __align__(16) float rs[4][R];
    __shared__ float wsh[4];
    int i = blockIdx.x, tid = threadIdx.x;
    int jbase = blockIdx.y * JCHUNK;
    int w = tid >> 6, l = tid & 63;
    ((float*)rs)[tid] = 0.f;
    float base = ngate_b[tid] + A[i * D + tid];
    float acc = 0.f;
    for (int j0 = jbase; j0 < jbase + JCHUNK; j0 += 4) {
        int j = j0 + w;
        int p = i * N + j;
        float wt = pos[p];
        if (l == 0) wsh[w] = wt;
        if (wt != 0.f) {
            float x0 = corr[p * 2], x1 = corr[p * 2 + 1];
            h1[w][l]      = fmaxf(0.f, fmaf(x1, rel_w1[RELH + l],      fmaf(x0, rel_w1[l],      rel_b1[l])));
            h1[w][l + 64] = fmaxf(0.f, fmaf(x1, rel_w1[RELH + l + 64], fmaf(x0, rel_w1[l + 64], rel_b1[l + 64])));
        }
        __syncthreads();
        if (wsh[w] != 0.f) {
            float c0 = rel_b2[l], c1 = 0.f, c2 = 0.f, c3 = 0.f;
            const float4* hv = (const float4*)h1[w];
            #pragma unroll 8
            for (int k4 = 0; k4 < RELH / 4; ++k4) {
                float4 h = hv[k4];
                int k = k4 * 4;
                c0 = fmaf(h.x, rel_w2[k * R + l], c0);
                c1 = fmaf(h.y, rel_w2[(k + 1) * R + l], c1);
                c2 = fmaf(h.z, rel_w2[(k + 2) * R + l], c2);
                c3 = fmaf(h.w, rel_w2[(k + 3) * R + l], c3);
            }
            rs[w][l] = fmaxf(0.f, (c0 + c1) + (c2 + c3));
        }
        __syncthreads();
        #pragma unroll
        for (int ww = 0; ww < 4; ++ww) {
            float wtj = wsh[ww];
            if (wtj != 0.f) {
                int jj = j0 + ww;
                const float4* rv = (const float4*)rs[ww];
                float l0 = 0.f, l1 = 0.f, l2 = 0.f, l3 = 0.f;
                #pragma unroll 4
                for (int m4 = 0; m4 < R / 4; ++m4) {
                    float4 r4 = rv[m4];
                    int m = m4 * 4;
                    l0 = fmaf(r4.x, ngate_w[m * D + tid], l0);
                    l1 = fmaf(r4.y, ngate_w[(m + 1) * D + tid], l1);
                    l2 = fmaf(r4.z, ngate_w[(m + 2) * D + tid], l2);
                    l3 = fmaf(r4.w, ngate_w[(m + 3) * D + tid], l3);
                }
                float logit = base + Bm[jj * D + tid] + ((l0 + l1) + (l2 + l3));
                float g = fast_sigmoid(logit);
                acc = fmaf(wtj * self_h[jj * D + tid], g, acc);
            }
        }
        __syncthreads();
    }
    partial[(blockIdx.y * N + i) * D + tid] = acc;
}

// ---------------------------------------------------------------------------
// hsum = sum of partials; hidden = relu(hsum@W1+b1); out2 = hidden@W2+b2;
// C = out2 + self_c; H_out = outgate * tanh(C); outputs = (outgate, H_out, C)
// ---------------------------------------------------------------------------
__global__ void final_kernel(const float* __restrict__ partial,
                             const float* __restrict__ wnei_w1, const float* __restrict__ wnei_b1,
                             const float* __restrict__ wnei_w2, const float* __restrict__ wnei_b2,
                             const float* __restrict__ self_c, const float* __restrict__ outgate,
                             float* __restrict__ out) {
    __shared__ __align__(16) float hs[D];
    __shared__ __align__(16) float hid[D];
    int i = blockIdx.x, d = threadIdx.x;
    float s = 0.f;
    #pragma unroll
    for (int c = 0; c < NCHUNK; ++c) s += partial[(c * N + i) * D + d];
    hs[d] = s;
    __syncthreads();
    float a0 = wnei_b1[d], a1 = 0.f, a2 = 0.f, a3 = 0.f;
    const float4* hv = (const float4*)hs;
    #pragma unroll 4
    for (int t4 = 0; t4 < D / 4; ++t4) {
        float4 h = hv[t4];
        int t = t4 * 4;
        a0 = fmaf(h.x, wnei_w1[t * D + d], a0);
        a1 = fmaf(h.y, wnei_w1[(t + 1) * D + d], a1);
        a2 = fmaf(h.z, wnei_w1[(t + 2) * D + d], a2);
        a3 = fmaf(h.w, wnei_w1[(t + 3) * D + d], a3);
    }
    hid[d] = fmaxf(0.f, (a0 + a1) + (a2 + a3));
    __syncthreads();
    float b0 = wnei_b2[d], b1 = 0.f, b2 = 0.f, b3 = 0.f;
    const float4* gv = (const float4*)hid;
    #pragma unroll 4
    for (int t4 = 0; t4 < D / 4; ++t4) {
        float4 h = gv[t4];
        int t = t4 * 4;
        b0 = fmaf(h.x, wnei_w2[t * D + d], b0);
        b1 = fmaf(h.y, wnei_w2[(t + 1) * D + d], b1);
        b2 = fmaf(h.z, wnei_w2[(t + 2) * D + d], b2);
        b3 = fmaf(h.w, wnei_w2[(t + 3) * D + d], b3);
    }
    int idx = i * D + d;
    float C = (b0 + b1) + (b2 + b3) + self_c[idx];
    float og = outgate[idx];
    out[idx] = og;
    out[ND + idx] = og * fast_tanh(C);
    out[2 * ND + idx] = C;
}

extern "C" void kernel_launch(void* const* d_in, const int* in_sizes, int n_in,
                              void* d_out, int out_size, void* d_ws, size_t ws_size,
                              hipStream_t stream) {
    const float* corr    = (const float*)d_in[0];
    const int*   nei     = (const int*)d_in[1];
    const float* outg    = (const float*)d_in[3];
    const float* self_h  = (const float*)d_in[4];
    const float* self_c  = (const float*)d_in[5];
    const float* rel_w1  = (const float*)d_in[6];
    const float* rel_b1  = (const float*)d_in[7];
    const float* rel_w2  = (const float*)d_in[8];
    const float* rel_b2  = (const float*)d_in[9];
    const float* ngate_w = (const float*)d_in[10];
    const float* ngate_b = (const float*)d_in[11];
    const float* war_w   = (const float*)d_in[12];
    const float* war_b   = (const float*)d_in[13];
    const float* wnei_w1 = (const float*)d_in[14];
    const float* wnei_b1 = (const float*)d_in[15];
    const float* wnei_w2 = (const float*)d_in[16];
    const float* wnei_b2 = (const float*)d_in[17];

    float* ws      = (float*)d_ws;
    float* tt      = ws;                       // NN (fallback only)
    float* pos     = ws + NN;                  // NN
    float* A       = ws + 2 * NN;              // ND
    float* Bm      = ws + 2 * NN + ND;         // ND
    float* u       = ws + 2 * NN + 2 * ND;     // N
    float* v       = u + N;                    // N
    float* partial = v + N;                    // NCHUNK*ND
    float* tail    = partial + NCHUNK * ND;
    _Float16* rc16 = (_Float16*)tail;          // NN*R fp16
    _Float16* wf   = rc16 + (size_t)NN * R;    // 2*16*64*8 fp16
    size_t base_floats = (size_t)(2 * NN + 2 * ND + 2 * N + NCHUNK * ND);
    size_t need = (base_floats + ((size_t)NN * R + 2 * 16 * 64 * 8) / 2 + 16) * sizeof(float);
    bool use_rc = ws_size >= need;
    float* out = (float*)d_out;

    prep_kernel<<<62, 256, 0, stream>>>(self_h, ngate_w, war_w, A, Bm, u, v, wf);
    if (use_rc) {
        ttsm_kernel<<<N, 384, 0, stream>>>(corr, rel_w1, rel_b1, rel_w2, rel_b2,
                                           war_w, v, nei, pos, rc16);
        dim3 ggrid(N, NCHUNK);
        gate_mfma_kernel<<<ggrid, 256, 0, stream>>>(rc16, wf, ngate_b, A, Bm, pos, self_h,
                                                    partial);
    } else {
        tt_valu_kernel<<<NN / TPB, 256, 0, stream>>>(corr, rel_w1, rel_b1, rel_w2, rel_b2,
                                                     war_w, war_b, u, v, tt);
        softmax_kernel<<<N, 256, 0, stream>>>(tt, nei, pos);
        dim3 ggrid(N, NCHUNK);
        gate_norc_kernel<<<ggrid, 256, 0, stream>>>(corr, rel_w1, rel_b1, rel_w2, rel_b2,
                                                    ngate_w, ngate_b, A, Bm, pos, self_h,
                                                    partial);
    }
    final_kernel<<<N, 256, 0, stream>>>(partial, wnei_w1, wnei_b1, wnei_w2, wnei_b2,
                                        self_c, outg, out);
}